// Round 5
// baseline (326.856 us; speedup 1.0000x reference)
//
#include <hip/hip_runtime.h>
#include <hip/hip_fp16.h>

typedef _Float16 half8 __attribute__((ext_vector_type(8)));
typedef float floatx4 __attribute__((ext_vector_type(4)));

// ---------------- helpers ----------------

__device__ __forceinline__ void unpack8(uint4 v, float* f) {
    const __half2* hp = (const __half2*)&v;
    float2 a = __half22float2(hp[0]);
    float2 b = __half22float2(hp[1]);
    float2 c = __half22float2(hp[2]);
    float2 d = __half22float2(hp[3]);
    f[0] = a.x; f[1] = a.y; f[2] = b.x; f[3] = b.y;
    f[4] = c.x; f[5] = c.y; f[6] = d.x; f[7] = d.y;
}

__device__ __forceinline__ uint4 pack8(const float* f) {
    __half2 h0 = __floats2half2_rn(f[0], f[1]);
    __half2 h1 = __floats2half2_rn(f[2], f[3]);
    __half2 h2 = __floats2half2_rn(f[4], f[5]);
    __half2 h3 = __floats2half2_rn(f[6], f[7]);
    uint4 v;
    v.x = *(const unsigned int*)&h0;
    v.y = *(const unsigned int*)&h1;
    v.z = *(const unsigned int*)&h2;
    v.w = *(const unsigned int*)&h3;
    return v;
}

__global__ void k_zero4(float4* p, int n4) {
    int i = blockIdx.x * 256 + threadIdx.x;
    if (i < n4) p[i] = make_float4(0.f, 0.f, 0.f, 0.f);
}

__global__ void k_zeroi(int* p, int n) {
    int i = blockIdx.x * 256 + threadIdx.x;
    if (i < n) p[i] = 0;
}

// ---------------- bucketed CSR build ----------------
// bucket b = 16 consecutive dst nodes. B = N/16 buckets.

__global__ void k_hist(const int* __restrict__ dst, int* __restrict__ bcnt, int E) {
    int i = blockIdx.x * 256 + threadIdx.x;
    if (i < E) atomicAdd(&bcnt[dst[i] >> 4], 1);
}

__global__ void k_blocksum(const int* __restrict__ cnt, int* __restrict__ bsum, int n) {
    __shared__ int ls[256];
    int i = blockIdx.x * 256 + threadIdx.x;
    ls[threadIdx.x] = i < n ? cnt[i] : 0;
    __syncthreads();
    for (int off = 128; off > 0; off >>= 1) {
        if (threadIdx.x < off) ls[threadIdx.x] += ls[threadIdx.x + off];
        __syncthreads();
    }
    if (threadIdx.x == 0) bsum[blockIdx.x] = ls[0];
}

__global__ void k_scanbsum(int* bsum, int nb) {
    if (threadIdx.x == 0 && blockIdx.x == 0) {
        int acc = 0;
        for (int i = 0; i < nb; ++i) { int v = bsum[i]; bsum[i] = acc; acc += v; }
    }
}

__global__ void k_scanchunk(const int* __restrict__ cnt, const int* __restrict__ bsum,
                            int* __restrict__ bptr, int* __restrict__ bcur,
                            int n, int E) {
    __shared__ int ls[256];
    int i = blockIdx.x * 256 + threadIdx.x;
    int v = i < n ? cnt[i] : 0;
    ls[threadIdx.x] = v;
    __syncthreads();
    for (int off = 1; off < 256; off <<= 1) {
        int t = threadIdx.x >= off ? ls[threadIdx.x - off] : 0;
        __syncthreads();
        ls[threadIdx.x] += t;
        __syncthreads();
    }
    if (i < n) {
        int ex = ls[threadIdx.x] - v + bsum[blockIdx.x];
        bptr[i] = ex;
        bcur[i] = ex;
    }
    if (i == n - 1) bptr[n] = E;
}

// place (src, dst&15) packed into bucket-contiguous pair array
__global__ void k_placeb(const int* __restrict__ src, const int* __restrict__ dst,
                         int* __restrict__ bcur, unsigned int* __restrict__ pairs, int E) {
    int i = blockIdx.x * 256 + threadIdx.x;
    if (i < E) {
        int d = dst[i];
        int pos = atomicAdd(&bcur[d >> 4], 1);
        pairs[pos] = (unsigned int)src[i] | ((unsigned int)(d & 15) << 16);
    }
}

// per-bucket 16-bin sort: writes sidx (node-sorted), deg, row_ptr. One wave per bucket.
__global__ __launch_bounds__(256) void k_bsort(const unsigned int* __restrict__ pairs,
                                               const int* __restrict__ bptr,
                                               int* __restrict__ sidx,
                                               int* __restrict__ deg,
                                               int* __restrict__ row_ptr,
                                               int B, int E, int N) {
    __shared__ int hist[4][16];
    __shared__ int curs[4][16];
    int w = threadIdx.x >> 6, lane = threadIdx.x & 63;
    int b = blockIdx.x * 4 + w;
    bool act = b < B;
    int beg = act ? bptr[b] : 0;
    int end = act ? bptr[b + 1] : 0;
    if (lane < 16) hist[w][lane] = 0;
    __syncthreads();
    if (act)
        for (int j = beg + lane; j < end; j += 64)
            atomicAdd(&hist[w][pairs[j] >> 16], 1);
    __syncthreads();
    if (act && lane == 0) {
        int run = beg;
        for (int k = 0; k < 16; ++k) { curs[w][k] = run; run += hist[w][k]; }
    }
    __syncthreads();
    if (act && lane < 16) {
        int node = b * 16 + lane;
        deg[node] = hist[w][lane];
        row_ptr[node] = curs[w][lane];
    }
    if (blockIdx.x == 0 && threadIdx.x == 0) row_ptr[N] = E;
    if (act)
        for (int j = beg + lane; j < end; j += 64) {
            unsigned int u = pairs[j];
            int pos = atomicAdd(&curs[w][u >> 16], 1);
            sidx[pos] = (int)(u & 0xFFFFu);
        }
}

__global__ void k_dinv(const int* __restrict__ deg, float* __restrict__ dinv, int n) {
    int i = blockIdx.x * 256 + threadIdx.x;
    if (i < n) {
        int d = deg[i];
        dinv[i] = d > 0 ? rsqrtf((float)d) : 0.f;
    }
}

// ---------------- weight pack: W[k][Nw] fp32 -> Wt[Npad][128] fp16 ----------------

__global__ void k_packW(const float* __restrict__ W, __half* __restrict__ Wt,
                        int Nw, int Npad) {
    int i = blockIdx.x * 256 + threadIdx.x;
    if (i >= Npad * 128) return;
    int n = i >> 7, k = i & 127;
    Wt[i] = (n < Nw) ? __float2half(W[(size_t)k * Nw + n]) : __half(0.f);
}

// ---------------- MFMA GEMM (optional fused BN+ReLU on A) ----------------
// AMODE 0: A fp32, plain. AMODE 1: A fp16, a = relu(a*scale[c]+shift[c]).
// C[row][0..OUTW) fp16 = dinv[row] * (A'[row] @ W), K=128.

template <int CT, int OUTW, int AMODE>
__global__ __launch_bounds__(256) void k_gemm_mfma(const void* __restrict__ Ap,
                                                   const __half* __restrict__ Wt,
                                                   const float* __restrict__ scale,
                                                   const float* __restrict__ shift,
                                                   const float* __restrict__ dinv,
                                                   __half* __restrict__ C, int nrows) {
    __shared__ char lw[CT * 16 * 256];
    __shared__ float lsc[128], lsh[128];
    const int nu4 = CT * 16 * 16;
    for (int i = threadIdx.x; i < nu4; i += 256) {
        int row = i >> 4, k8 = i & 15;
        uint4 v = ((const uint4*)Wt)[i];
        *(uint4*)(lw + ((row * 256 + k8 * 16) ^ ((row & 7) << 4))) = v;
    }
    if (AMODE == 1 && threadIdx.x < 128) {
        lsc[threadIdx.x] = scale[threadIdx.x];
        lsh[threadIdx.x] = shift[threadIdx.x];
    }
    __syncthreads();

    const int lane = threadIdx.x & 63;
    const int wid = threadIdx.x >> 6;
    const int l15 = lane & 15;
    const int lg = lane >> 4;
    const int rowbase = blockIdx.x * 128 + wid * 32;

    floatx4 acc[2][CT];
#pragma unroll
    for (int r = 0; r < 2; ++r)
#pragma unroll
        for (int c = 0; c < CT; ++c) acc[r][c] = (floatx4){0.f, 0.f, 0.f, 0.f};

    for (int kk = 0; kk < 4; ++kk) {
        half8 afrag[2];
        const int c0 = kk * 32 + lg * 8;
#pragma unroll
        for (int r = 0; r < 2; ++r) {
            int row = rowbase + r * 16 + l15;
            half8 h = {0, 0, 0, 0, 0, 0, 0, 0};
            if (row < nrows) {
                if (AMODE == 0) {
                    const float* a = (const float*)Ap + (size_t)row * 128 + c0;
                    float4 v0 = *(const float4*)a;
                    float4 v1 = *(const float4*)(a + 4);
                    h[0] = (_Float16)v0.x; h[1] = (_Float16)v0.y;
                    h[2] = (_Float16)v0.z; h[3] = (_Float16)v0.w;
                    h[4] = (_Float16)v1.x; h[5] = (_Float16)v1.y;
                    h[6] = (_Float16)v1.z; h[7] = (_Float16)v1.w;
                } else {
                    uint4 raw = *(const uint4*)((const __half*)Ap + (size_t)row * 128 + c0);
                    float f[8];
                    unpack8(raw, f);
                    float4 s0 = *(const float4*)&lsc[c0];
                    float4 s1 = *(const float4*)&lsc[c0 + 4];
                    float4 t0 = *(const float4*)&lsh[c0];
                    float4 t1 = *(const float4*)&lsh[c0 + 4];
                    h[0] = (_Float16)fmaxf(f[0] * s0.x + t0.x, 0.f);
                    h[1] = (_Float16)fmaxf(f[1] * s0.y + t0.y, 0.f);
                    h[2] = (_Float16)fmaxf(f[2] * s0.z + t0.z, 0.f);
                    h[3] = (_Float16)fmaxf(f[3] * s0.w + t0.w, 0.f);
                    h[4] = (_Float16)fmaxf(f[4] * s1.x + t1.x, 0.f);
                    h[5] = (_Float16)fmaxf(f[5] * s1.y + t1.y, 0.f);
                    h[6] = (_Float16)fmaxf(f[6] * s1.z + t1.z, 0.f);
                    h[7] = (_Float16)fmaxf(f[7] * s1.w + t1.w, 0.f);
                }
            }
            afrag[r] = h;
        }
#pragma unroll
        for (int c = 0; c < CT; ++c) {
            int wrow = c * 16 + l15;
            half8 bfrag = *(const half8*)(lw + ((wrow * 256 + kk * 64 + lg * 16) ^ ((wrow & 7) << 4)));
#pragma unroll
            for (int r = 0; r < 2; ++r)
                acc[r][c] = __builtin_amdgcn_mfma_f32_16x16x32_f16(afrag[r], bfrag, acc[r][c], 0, 0, 0);
        }
    }

#pragma unroll
    for (int r = 0; r < 2; ++r) {
        int rbase = rowbase + r * 16 + lg * 4;
        float d4[4];
#pragma unroll
        for (int j = 0; j < 4; ++j)
            d4[j] = (rbase + j) < nrows ? dinv[rbase + j] : 0.f;
#pragma unroll
        for (int c = 0; c < CT; ++c) {
            int col = c * 16 + l15;
            if (OUTW != CT * 16 && col >= OUTW) continue;
#pragma unroll
            for (int j = 0; j < 4; ++j) {
                int row = rbase + j;
                if (row < nrows)
                    C[(size_t)row * OUTW + col] = __float2half(acc[r][c][j] * d4[j]);
            }
        }
    }
}

// ---------------- aggregation + fused BN stats ----------------
// Hout[d] = fp16(dinv[d]*sum M[sidx[j]]); block also reduces sum/sumsq into
// 32-way shadow accumulators (selected by blockIdx&31).

__global__ __launch_bounds__(256) void k_agg128_stats(const __half* __restrict__ M,
                                                      const int* __restrict__ rp,
                                                      const int* __restrict__ sidx,
                                                      const float* __restrict__ dinv,
                                                      __half* __restrict__ Hout,
                                                      float* __restrict__ sums32,
                                                      float* __restrict__ sumsq32, int n) {
    int d = blockIdx.x * 16 + (threadIdx.x >> 4);
    int lane = threadIdx.x & 15;
    float acc[8] = {0.f, 0.f, 0.f, 0.f, 0.f, 0.f, 0.f, 0.f};
    if (d < n) {
        int beg = rp[d], end = rp[d + 1];
        for (int j = beg; j < end; ++j) {
            int s = sidx[j];
            uint4 v = *(const uint4*)(M + (size_t)s * 128 + lane * 8);
            float f[8];
            unpack8(v, f);
#pragma unroll
            for (int i = 0; i < 8; ++i) acc[i] += f[i];
        }
        float sc = dinv[d];
#pragma unroll
        for (int i = 0; i < 8; ++i) acc[i] *= sc;
        *(uint4*)(Hout + (size_t)d * 128 + lane * 8) = pack8(acc);
    }
    __shared__ float ls[256][8];
    __shared__ float lq[256][8];
#pragma unroll
    for (int i = 0; i < 8; ++i) {
        ls[threadIdx.x][i] = acc[i];
        lq[threadIdx.x][i] = acc[i] * acc[i];
    }
    __syncthreads();
    if (threadIdx.x < 128) {
        int c = threadIdx.x;
        int lc = c >> 3, e = c & 7;
        float ss = 0.f, qq = 0.f;
        for (int r = 0; r < 16; ++r) {
            ss += ls[r * 16 + lc][e];
            qq += lq[r * 16 + lc][e];
        }
        int sh = (blockIdx.x & 31) * 128;
        atomicAdd(&sums32[sh + c], ss);
        atomicAdd(&sumsq32[sh + c], qq);
    }
}

__global__ void k_bnfinal32(const float* __restrict__ sums32, const float* __restrict__ sumsq32,
                            const float* __restrict__ g, const float* __restrict__ beta,
                            float* __restrict__ scale, float* __restrict__ shift, int nrows) {
    int c = threadIdx.x;
    float s = 0.f, q = 0.f;
    for (int k = 0; k < 32; ++k) { s += sums32[k * 128 + c]; q += sumsq32[k * 128 + c]; }
    float inv_n = 1.f / (float)nrows;
    float mu = s * inv_n;
    float var = q * inv_n - mu * mu;
    float rs = rsqrtf(var + 1e-5f);
    float sc = rs * g[c];
    scale[c] = sc;
    shift[c] = beta[c] - mu * sc;
}

// ---------------- layer-3 aggregation ----------------

__global__ void k_agg40_f16(const __half* __restrict__ M,
                            const int* __restrict__ rp,
                            const int* __restrict__ sidx,
                            const float* __restrict__ dinv,
                            const float* __restrict__ b3,
                            float* __restrict__ out, int n) {
    int i = blockIdx.x * 256 + threadIdx.x;
    if (i >= n * 5) return;
    int d = i / 5, q = i % 5;
    int beg = rp[d], end = rp[d + 1];
    float acc[8] = {0.f, 0.f, 0.f, 0.f, 0.f, 0.f, 0.f, 0.f};
    for (int j = beg; j < end; ++j) {
        int s = sidx[j];
        uint4 v = *(const uint4*)(M + (size_t)s * 40 + q * 8);
        float f[8];
        unpack8(v, f);
#pragma unroll
        for (int k = 0; k < 8; ++k) acc[k] += f[k];
    }
    float sc = dinv[d];
    float4 b0 = *(const float4*)&b3[q * 8];
    float4 b1 = *(const float4*)&b3[q * 8 + 4];
    float4 r0, r1;
    r0.x = acc[0] * sc + b0.x; r0.y = acc[1] * sc + b0.y;
    r0.z = acc[2] * sc + b0.z; r0.w = acc[3] * sc + b0.w;
    r1.x = acc[4] * sc + b1.x; r1.y = acc[5] * sc + b1.y;
    r1.z = acc[6] * sc + b1.z; r1.w = acc[7] * sc + b1.w;
    float* o = out + (size_t)d * 40 + q * 8;
    *(float4*)o = r0;
    *(float4*)(o + 4) = r1;
}

// ---------------- launch ----------------

extern "C" void kernel_launch(void* const* d_in, const int* in_sizes, int n_in,
                              void* d_out, int out_size, void* d_ws, size_t ws_size,
                              hipStream_t stream) {
    const float* x  = (const float*)d_in[0];
    const int*   ei = (const int*)d_in[1];
    const float* W1 = (const float*)d_in[2];
    const float* g1 = (const float*)d_in[4];
    const float* be1= (const float*)d_in[5];
    const float* W2 = (const float*)d_in[6];
    const float* g2 = (const float*)d_in[8];
    const float* be2= (const float*)d_in[9];
    const float* W3 = (const float*)d_in[10];
    const float* b3 = (const float*)d_in[11];

    const int N = in_sizes[0] / 128;
    const int E = in_sizes[1] / 2;
    const int* srcv = ei;
    const int* dstv = ei + E;
    const int B = (N + 15) / 16;             // buckets of 16 dst nodes
    const int NBb = (B + 255) / 256;

    __half* M    = (__half*)d_ws;                 // N*128
    __half* Hb   = M + (size_t)N * 128;           // N*128
    __half* t3   = Hb + (size_t)N * 128;          // N*40
    __half* Wt1  = t3 + (size_t)N * 40;           // 128*128
    __half* Wt2  = Wt1 + 128 * 128;
    __half* Wt3  = Wt2 + 128 * 128;               // 48*128
    float* dinv    = (float*)(Wt3 + 48 * 128);
    int*   deg     = (int*)(dinv + N);
    int*   row_ptr = deg + N;            // N+1
    int*   sidx    = row_ptr + N + 1;    // E
    unsigned int* pairs = (unsigned int*)(sidx + E);  // E
    int*   bcnt    = (int*)(pairs + E);  // B
    int*   bptr    = bcnt + B;           // B+1
    int*   bcur    = bptr + B + 1;       // B
    int*   bsum    = bcur + B;           // NBb
    float* sums32  = (float*)(bsum + NBb + 1); // 32*128
    float* sumsq32 = sums32 + 32 * 128;        // 32*128
    float* scale   = sumsq32 + 32 * 128;       // 128
    float* shift   = scale + 128;              // 128
    float* out     = (float*)d_out;

    const int GB = (N + 127) / 128;

    // ---- weight packs ----
    k_packW<<<(128 * 128 + 255) / 256, 256, 0, stream>>>(W1, Wt1, 128, 128);
    k_packW<<<(128 * 128 + 255) / 256, 256, 0, stream>>>(W2, Wt2, 128, 128);
    k_packW<<<(48 * 128 + 255) / 256, 256, 0, stream>>>(W3, Wt3, 40, 48);

    // ---- bucketed CSR build ----
    k_zeroi<<<(B + 255) / 256, 256, 0, stream>>>(bcnt, B);
    k_hist<<<(E + 255) / 256, 256, 0, stream>>>(dstv, bcnt, E);
    k_blocksum<<<NBb, 256, 0, stream>>>(bcnt, bsum, B);
    k_scanbsum<<<1, 64, 0, stream>>>(bsum, NBb);
    k_scanchunk<<<NBb, 256, 0, stream>>>(bcnt, bsum, bptr, bcur, B, E);
    k_placeb<<<(E + 255) / 256, 256, 0, stream>>>(srcv, dstv, bcur, pairs, E);
    k_bsort<<<(B + 3) / 4, 256, 0, stream>>>(pairs, bptr, sidx, deg, row_ptr, B, E, N);
    k_dinv<<<(N + 255) / 256, 256, 0, stream>>>(deg, dinv, N);

    // ---- layer 1 ----
    k_zero4<<<(2048 + 255) / 256, 256, 0, stream>>>((float4*)sums32, 2048);
    k_gemm_mfma<8, 128, 0><<<GB, 256, 0, stream>>>(x, Wt1, nullptr, nullptr, dinv, M, N);
    k_agg128_stats<<<(N + 15) / 16, 256, 0, stream>>>(M, row_ptr, sidx, dinv, Hb, sums32, sumsq32, N);
    k_bnfinal32<<<1, 128, 0, stream>>>(sums32, sumsq32, g1, be1, scale, shift, N);

    // ---- layer 2 ----
    k_gemm_mfma<8, 128, 1><<<GB, 256, 0, stream>>>(Hb, Wt2, scale, shift, dinv, M, N);
    k_zero4<<<(2048 + 255) / 256, 256, 0, stream>>>((float4*)sums32, 2048);
    k_agg128_stats<<<(N + 15) / 16, 256, 0, stream>>>(M, row_ptr, sidx, dinv, Hb, sums32, sumsq32, N);
    k_bnfinal32<<<1, 128, 0, stream>>>(sums32, sumsq32, g2, be2, scale, shift, N);

    // ---- layer 3 ----
    k_gemm_mfma<3, 40, 1><<<GB, 256, 0, stream>>>(Hb, Wt3, scale, shift, dinv, t3, N);
    k_agg40_f16<<<(N * 5 + 255) / 256, 256, 0, stream>>>(t3, row_ptr, sidx, dinv, b3, out, N);
}

// Round 6
// 271.200 us; speedup vs baseline: 1.2052x; 1.2052x over previous
//
#include <hip/hip_runtime.h>
#include <hip/hip_fp16.h>

typedef _Float16 half8 __attribute__((ext_vector_type(8)));
typedef float floatx4 __attribute__((ext_vector_type(4)));

// ---------------- helpers ----------------

__device__ __forceinline__ void unpack8(uint4 v, float* f) {
    const __half2* hp = (const __half2*)&v;
    float2 a = __half22float2(hp[0]);
    float2 b = __half22float2(hp[1]);
    float2 c = __half22float2(hp[2]);
    float2 d = __half22float2(hp[3]);
    f[0] = a.x; f[1] = a.y; f[2] = b.x; f[3] = b.y;
    f[4] = c.x; f[5] = c.y; f[6] = d.x; f[7] = d.y;
}

__device__ __forceinline__ uint4 pack8(const float* f) {
    __half2 h0 = __floats2half2_rn(f[0], f[1]);
    __half2 h1 = __floats2half2_rn(f[2], f[3]);
    __half2 h2 = __floats2half2_rn(f[4], f[5]);
    __half2 h3 = __floats2half2_rn(f[6], f[7]);
    uint4 v;
    v.x = *(const unsigned int*)&h0;
    v.y = *(const unsigned int*)&h1;
    v.z = *(const unsigned int*)&h2;
    v.w = *(const unsigned int*)&h3;
    return v;
}

__global__ void k_zero4(float4* p, int n4) {
    int i = blockIdx.x * 256 + threadIdx.x;
    if (i < n4) p[i] = make_float4(0.f, 0.f, 0.f, 0.f);
}

__global__ void k_zeroi(int* p, int n) {
    int i = blockIdx.x * 256 + threadIdx.x;
    if (i < n) p[i] = 0;
}

// ---------------- CSR build (counting sort, XCD-range-partitioned) ----------------
// block b: edge chunk (b>>3), dst range (b&7)*rs .. +rs. With blockIdx%8 -> XCD
// round-robin, all stores/atomics to a given deg/cursor/sidx line stay on one XCD.

__global__ void k_deg_xcd(const int* __restrict__ dst, int* __restrict__ deg,
                          int E, int rs) {
    int lo = (blockIdx.x & 7) * rs;
    int i = (blockIdx.x >> 3) * 256 + threadIdx.x;
    if (i < E) {
        int d = dst[i];
        if (d >= lo && d < lo + rs) atomicAdd(&deg[d], 1);
    }
}

__global__ void k_place_xcd(const int* __restrict__ src, const int* __restrict__ dst,
                            int* __restrict__ cursor, int* __restrict__ sidx,
                            int E, int rs) {
    int lo = (blockIdx.x & 7) * rs;
    int i = (blockIdx.x >> 3) * 256 + threadIdx.x;
    if (i < E) {
        int d = dst[i];
        if (d >= lo && d < lo + rs) {
            int pos = atomicAdd(&cursor[d], 1);
            sidx[pos] = src[i];
        }
    }
}

__global__ void k_dinv(const int* __restrict__ deg, float* __restrict__ dinv, int n) {
    int i = blockIdx.x * 256 + threadIdx.x;
    if (i < n) {
        int d = deg[i];
        dinv[i] = d > 0 ? rsqrtf((float)d) : 0.f;
    }
}

__global__ void k_blocksum(const int* __restrict__ cnt, int* __restrict__ bsum, int n) {
    __shared__ int ls[256];
    int i = blockIdx.x * 256 + threadIdx.x;
    ls[threadIdx.x] = i < n ? cnt[i] : 0;
    __syncthreads();
    for (int off = 128; off > 0; off >>= 1) {
        if (threadIdx.x < off) ls[threadIdx.x] += ls[threadIdx.x + off];
        __syncthreads();
    }
    if (threadIdx.x == 0) bsum[blockIdx.x] = ls[0];
}

__global__ void k_scanbsum(int* bsum, int nb) {
    if (threadIdx.x == 0 && blockIdx.x == 0) {
        int acc = 0;
        for (int i = 0; i < nb; ++i) { int v = bsum[i]; bsum[i] = acc; acc += v; }
    }
}

__global__ void k_scanchunk(const int* __restrict__ cnt, const int* __restrict__ bsum,
                            int* __restrict__ row_ptr, int* __restrict__ cursor,
                            int n, int E) {
    __shared__ int ls[256];
    int i = blockIdx.x * 256 + threadIdx.x;
    int v = i < n ? cnt[i] : 0;
    ls[threadIdx.x] = v;
    __syncthreads();
    for (int off = 1; off < 256; off <<= 1) {
        int t = threadIdx.x >= off ? ls[threadIdx.x - off] : 0;
        __syncthreads();
        ls[threadIdx.x] += t;
        __syncthreads();
    }
    if (i < n) {
        int ex = ls[threadIdx.x] - v + bsum[blockIdx.x];
        row_ptr[i] = ex;
        cursor[i] = ex;
    }
    if (i == n - 1) row_ptr[n] = E;
}

// ---------------- weight pack: W[k][Nw] fp32 -> Wt[Npad][128] fp16 ----------------

__global__ void k_packW(const float* __restrict__ W, __half* __restrict__ Wt,
                        int Nw, int Npad) {
    int i = blockIdx.x * 256 + threadIdx.x;
    if (i >= Npad * 128) return;
    int n = i >> 7, k = i & 127;
    Wt[i] = (n < Nw) ? __float2half(W[(size_t)k * Nw + n]) : __half(0.f);
}

// ---------------- MFMA GEMM (optional fused BN+ReLU on A) ----------------
// AMODE 0: A fp32, plain. AMODE 1: A fp16, a = relu(a*scale[c]+shift[c]).
// C[row][0..OUTW) fp16 = dinv[row] * (A'[row] @ W), K=128.

template <int CT, int OUTW, int AMODE>
__global__ __launch_bounds__(256) void k_gemm_mfma(const void* __restrict__ Ap,
                                                   const __half* __restrict__ Wt,
                                                   const float* __restrict__ scale,
                                                   const float* __restrict__ shift,
                                                   const float* __restrict__ dinv,
                                                   __half* __restrict__ C, int nrows) {
    __shared__ char lw[CT * 16 * 256];
    __shared__ float lsc[128], lsh[128];
    const int nu4 = CT * 16 * 16;
    for (int i = threadIdx.x; i < nu4; i += 256) {
        int row = i >> 4, k8 = i & 15;
        uint4 v = ((const uint4*)Wt)[i];
        *(uint4*)(lw + ((row * 256 + k8 * 16) ^ ((row & 7) << 4))) = v;
    }
    if (AMODE == 1 && threadIdx.x < 128) {
        lsc[threadIdx.x] = scale[threadIdx.x];
        lsh[threadIdx.x] = shift[threadIdx.x];
    }
    __syncthreads();

    const int lane = threadIdx.x & 63;
    const int wid = threadIdx.x >> 6;
    const int l15 = lane & 15;
    const int lg = lane >> 4;
    const int rowbase = blockIdx.x * 128 + wid * 32;

    floatx4 acc[2][CT];
#pragma unroll
    for (int r = 0; r < 2; ++r)
#pragma unroll
        for (int c = 0; c < CT; ++c) acc[r][c] = (floatx4){0.f, 0.f, 0.f, 0.f};

    for (int kk = 0; kk < 4; ++kk) {
        half8 afrag[2];
        const int c0 = kk * 32 + lg * 8;
#pragma unroll
        for (int r = 0; r < 2; ++r) {
            int row = rowbase + r * 16 + l15;
            half8 h = {0, 0, 0, 0, 0, 0, 0, 0};
            if (row < nrows) {
                if (AMODE == 0) {
                    const float* a = (const float*)Ap + (size_t)row * 128 + c0;
                    float4 v0 = *(const float4*)a;
                    float4 v1 = *(const float4*)(a + 4);
                    h[0] = (_Float16)v0.x; h[1] = (_Float16)v0.y;
                    h[2] = (_Float16)v0.z; h[3] = (_Float16)v0.w;
                    h[4] = (_Float16)v1.x; h[5] = (_Float16)v1.y;
                    h[6] = (_Float16)v1.z; h[7] = (_Float16)v1.w;
                } else {
                    uint4 raw = *(const uint4*)((const __half*)Ap + (size_t)row * 128 + c0);
                    float f[8];
                    unpack8(raw, f);
                    float4 s0 = *(const float4*)&lsc[c0];
                    float4 s1 = *(const float4*)&lsc[c0 + 4];
                    float4 t0 = *(const float4*)&lsh[c0];
                    float4 t1 = *(const float4*)&lsh[c0 + 4];
                    h[0] = (_Float16)fmaxf(f[0] * s0.x + t0.x, 0.f);
                    h[1] = (_Float16)fmaxf(f[1] * s0.y + t0.y, 0.f);
                    h[2] = (_Float16)fmaxf(f[2] * s0.z + t0.z, 0.f);
                    h[3] = (_Float16)fmaxf(f[3] * s0.w + t0.w, 0.f);
                    h[4] = (_Float16)fmaxf(f[4] * s1.x + t1.x, 0.f);
                    h[5] = (_Float16)fmaxf(f[5] * s1.y + t1.y, 0.f);
                    h[6] = (_Float16)fmaxf(f[6] * s1.z + t1.z, 0.f);
                    h[7] = (_Float16)fmaxf(f[7] * s1.w + t1.w, 0.f);
                }
            }
            afrag[r] = h;
        }
#pragma unroll
        for (int c = 0; c < CT; ++c) {
            int wrow = c * 16 + l15;
            half8 bfrag = *(const half8*)(lw + ((wrow * 256 + kk * 64 + lg * 16) ^ ((wrow & 7) << 4)));
#pragma unroll
            for (int r = 0; r < 2; ++r)
                acc[r][c] = __builtin_amdgcn_mfma_f32_16x16x32_f16(afrag[r], bfrag, acc[r][c], 0, 0, 0);
        }
    }

#pragma unroll
    for (int r = 0; r < 2; ++r) {
        int rbase = rowbase + r * 16 + lg * 4;
        float d4[4];
#pragma unroll
        for (int j = 0; j < 4; ++j)
            d4[j] = (rbase + j) < nrows ? dinv[rbase + j] : 0.f;
#pragma unroll
        for (int c = 0; c < CT; ++c) {
            int col = c * 16 + l15;
            if (OUTW != CT * 16 && col >= OUTW) continue;
#pragma unroll
            for (int j = 0; j < 4; ++j) {
                int row = rbase + j;
                if (row < nrows)
                    C[(size_t)row * OUTW + col] = __float2half(acc[r][c][j] * d4[j]);
            }
        }
    }
}

// ---------------- aggregation + fused BN stats ----------------

__global__ __launch_bounds__(256) void k_agg128_stats(const __half* __restrict__ M,
                                                      const int* __restrict__ rp,
                                                      const int* __restrict__ sidx,
                                                      const float* __restrict__ dinv,
                                                      __half* __restrict__ Hout,
                                                      float* __restrict__ sums32,
                                                      float* __restrict__ sumsq32, int n) {
    int d = blockIdx.x * 16 + (threadIdx.x >> 4);
    int lane = threadIdx.x & 15;
    float acc[8] = {0.f, 0.f, 0.f, 0.f, 0.f, 0.f, 0.f, 0.f};
    if (d < n) {
        int beg = rp[d], end = rp[d + 1];
        for (int j = beg; j < end; ++j) {
            int s = sidx[j];
            uint4 v = *(const uint4*)(M + (size_t)s * 128 + lane * 8);
            float f[8];
            unpack8(v, f);
#pragma unroll
            for (int i = 0; i < 8; ++i) acc[i] += f[i];
        }
        float sc = dinv[d];
#pragma unroll
        for (int i = 0; i < 8; ++i) acc[i] *= sc;
        *(uint4*)(Hout + (size_t)d * 128 + lane * 8) = pack8(acc);
    }
    __shared__ float ls[256][8];
    __shared__ float lq[256][8];
#pragma unroll
    for (int i = 0; i < 8; ++i) {
        ls[threadIdx.x][i] = acc[i];
        lq[threadIdx.x][i] = acc[i] * acc[i];
    }
    __syncthreads();
    if (threadIdx.x < 128) {
        int c = threadIdx.x;
        int lc = c >> 3, e = c & 7;
        float ss = 0.f, qq = 0.f;
        for (int r = 0; r < 16; ++r) {
            ss += ls[r * 16 + lc][e];
            qq += lq[r * 16 + lc][e];
        }
        int sh = (blockIdx.x & 31) * 128;
        atomicAdd(&sums32[sh + c], ss);
        atomicAdd(&sumsq32[sh + c], qq);
    }
}

__global__ void k_bnfinal32(const float* __restrict__ sums32, const float* __restrict__ sumsq32,
                            const float* __restrict__ g, const float* __restrict__ beta,
                            float* __restrict__ scale, float* __restrict__ shift, int nrows) {
    int c = threadIdx.x;
    float s = 0.f, q = 0.f;
    for (int k = 0; k < 32; ++k) { s += sums32[k * 128 + c]; q += sumsq32[k * 128 + c]; }
    float inv_n = 1.f / (float)nrows;
    float mu = s * inv_n;
    float var = q * inv_n - mu * mu;
    float rs = rsqrtf(var + 1e-5f);
    float sc = rs * g[c];
    scale[c] = sc;
    shift[c] = beta[c] - mu * sc;
}

// ---------------- layer-3 aggregation ----------------

__global__ void k_agg40_f16(const __half* __restrict__ M,
                            const int* __restrict__ rp,
                            const int* __restrict__ sidx,
                            const float* __restrict__ dinv,
                            const float* __restrict__ b3,
                            float* __restrict__ out, int n) {
    int i = blockIdx.x * 256 + threadIdx.x;
    if (i >= n * 5) return;
    int d = i / 5, q = i % 5;
    int beg = rp[d], end = rp[d + 1];
    float acc[8] = {0.f, 0.f, 0.f, 0.f, 0.f, 0.f, 0.f, 0.f};
    for (int j = beg; j < end; ++j) {
        int s = sidx[j];
        uint4 v = *(const uint4*)(M + (size_t)s * 40 + q * 8);
        float f[8];
        unpack8(v, f);
#pragma unroll
        for (int k = 0; k < 8; ++k) acc[k] += f[k];
    }
    float sc = dinv[d];
    float4 b0 = *(const float4*)&b3[q * 8];
    float4 b1 = *(const float4*)&b3[q * 8 + 4];
    float4 r0, r1;
    r0.x = acc[0] * sc + b0.x; r0.y = acc[1] * sc + b0.y;
    r0.z = acc[2] * sc + b0.z; r0.w = acc[3] * sc + b0.w;
    r1.x = acc[4] * sc + b1.x; r1.y = acc[5] * sc + b1.y;
    r1.z = acc[6] * sc + b1.z; r1.w = acc[7] * sc + b1.w;
    float* o = out + (size_t)d * 40 + q * 8;
    *(float4*)o = r0;
    *(float4*)(o + 4) = r1;
}

// ---------------- launch ----------------

extern "C" void kernel_launch(void* const* d_in, const int* in_sizes, int n_in,
                              void* d_out, int out_size, void* d_ws, size_t ws_size,
                              hipStream_t stream) {
    const float* x  = (const float*)d_in[0];
    const int*   ei = (const int*)d_in[1];
    const float* W1 = (const float*)d_in[2];
    const float* g1 = (const float*)d_in[4];
    const float* be1= (const float*)d_in[5];
    const float* W2 = (const float*)d_in[6];
    const float* g2 = (const float*)d_in[8];
    const float* be2= (const float*)d_in[9];
    const float* W3 = (const float*)d_in[10];
    const float* b3 = (const float*)d_in[11];

    const int N = in_sizes[0] / 128;
    const int E = in_sizes[1] / 2;
    const int* srcv = ei;
    const int* dstv = ei + E;
    const int NB = (N + 255) / 256;
    const int RS = (N + 7) / 8;                 // per-XCD dst range
    const int EB8 = 8 * ((E + 255) / 256);      // xcd-partitioned edge grids

    __half* M    = (__half*)d_ws;                 // N*128
    __half* Hb   = M + (size_t)N * 128;           // N*128
    __half* t3   = Hb + (size_t)N * 128;          // N*40
    __half* Wt1  = t3 + (size_t)N * 40;           // 128*128
    __half* Wt2  = Wt1 + 128 * 128;
    __half* Wt3  = Wt2 + 128 * 128;               // 48*128
    float* dinv    = (float*)(Wt3 + 48 * 128);
    int*   deg     = (int*)(dinv + N);
    int*   row_ptr = deg + N;            // N+1
    int*   cursor  = row_ptr + N + 1;    // N
    int*   sidx    = cursor + N;         // E
    int*   bsum    = sidx + E;           // NB
    float* sums32  = (float*)(bsum + NB + 1); // 32*128
    float* sumsq32 = sums32 + 32 * 128;       // 32*128
    float* scale   = sumsq32 + 32 * 128;      // 128
    float* shift   = scale + 128;             // 128
    float* out     = (float*)d_out;

    const int GB = (N + 127) / 128;

    // ---- weight packs ----
    k_packW<<<(128 * 128 + 255) / 256, 256, 0, stream>>>(W1, Wt1, 128, 128);
    k_packW<<<(128 * 128 + 255) / 256, 256, 0, stream>>>(W2, Wt2, 128, 128);
    k_packW<<<(48 * 128 + 255) / 256, 256, 0, stream>>>(W3, Wt3, 40, 48);

    // ---- CSR build (XCD-partitioned counting sort) ----
    k_zeroi<<<(N + 255) / 256, 256, 0, stream>>>(deg, N);
    k_deg_xcd<<<EB8, 256, 0, stream>>>(dstv, deg, E, RS);
    k_dinv<<<(N + 255) / 256, 256, 0, stream>>>(deg, dinv, N);
    k_blocksum<<<NB, 256, 0, stream>>>(deg, bsum, N);
    k_scanbsum<<<1, 64, 0, stream>>>(bsum, NB);
    k_scanchunk<<<NB, 256, 0, stream>>>(deg, bsum, row_ptr, cursor, N, E);
    k_place_xcd<<<EB8, 256, 0, stream>>>(srcv, dstv, cursor, sidx, E, RS);

    // ---- layer 1 ----
    k_zero4<<<(2048 + 255) / 256, 256, 0, stream>>>((float4*)sums32, 2048);
    k_gemm_mfma<8, 128, 0><<<GB, 256, 0, stream>>>(x, Wt1, nullptr, nullptr, dinv, M, N);
    k_agg128_stats<<<(N + 15) / 16, 256, 0, stream>>>(M, row_ptr, sidx, dinv, Hb, sums32, sumsq32, N);
    k_bnfinal32<<<1, 128, 0, stream>>>(sums32, sumsq32, g1, be1, scale, shift, N);

    // ---- layer 2 ----
    k_gemm_mfma<8, 128, 1><<<GB, 256, 0, stream>>>(Hb, Wt2, scale, shift, dinv, M, N);
    k_zero4<<<(2048 + 255) / 256, 256, 0, stream>>>((float4*)sums32, 2048);
    k_agg128_stats<<<(N + 15) / 16, 256, 0, stream>>>(M, row_ptr, sidx, dinv, Hb, sums32, sumsq32, N);
    k_bnfinal32<<<1, 128, 0, stream>>>(sums32, sumsq32, g2, be2, scale, shift, N);

    // ---- layer 3 ----
    k_gemm_mfma<3, 40, 1><<<GB, 256, 0, stream>>>(Hb, Wt3, scale, shift, dinv, t3, N);
    k_agg40_f16<<<(N * 5 + 255) / 256, 256, 0, stream>>>(t3, row_ptr, sidx, dinv, b3, out, N);
}

// Round 7
// 247.381 us; speedup vs baseline: 1.3213x; 1.0963x over previous
//
#include <hip/hip_runtime.h>
#include <hip/hip_fp16.h>

typedef _Float16 half8 __attribute__((ext_vector_type(8)));
typedef float floatx4 __attribute__((ext_vector_type(4)));

// ---------------- helpers ----------------

__device__ __forceinline__ void unpack8(uint4 v, float* f) {
    const __half2* hp = (const __half2*)&v;
    float2 a = __half22float2(hp[0]);
    float2 b = __half22float2(hp[1]);
    float2 c = __half22float2(hp[2]);
    float2 d = __half22float2(hp[3]);
    f[0] = a.x; f[1] = a.y; f[2] = b.x; f[3] = b.y;
    f[4] = c.x; f[5] = c.y; f[6] = d.x; f[7] = d.y;
}

__device__ __forceinline__ uint4 pack8(const float* f) {
    __half2 h0 = __floats2half2_rn(f[0], f[1]);
    __half2 h1 = __floats2half2_rn(f[2], f[3]);
    __half2 h2 = __floats2half2_rn(f[4], f[5]);
    __half2 h3 = __floats2half2_rn(f[6], f[7]);
    uint4 v;
    v.x = *(const unsigned int*)&h0;
    v.y = *(const unsigned int*)&h1;
    v.z = *(const unsigned int*)&h2;
    v.w = *(const unsigned int*)&h3;
    return v;
}

__global__ void k_zero4(float4* p, int n4) {
    int i = blockIdx.x * 256 + threadIdx.x;
    if (i < n4) p[i] = make_float4(0.f, 0.f, 0.f, 0.f);
}

__global__ void k_zeroi(int* p, int n) {
    int i = blockIdx.x * 256 + threadIdx.x;
    if (i < n) p[i] = 0;
}

// ---------------- CSR build (counting sort, XCD-range-partitioned) ----------------
// block b: edge chunk (b>>3), dst range (b&7)*rs .. +rs. With blockIdx%8 -> XCD
// round-robin, all stores/atomics to a given deg/cursor/sidx line stay on one XCD.

__global__ void k_deg_xcd(const int* __restrict__ dst, int* __restrict__ deg,
                          int E, int rs) {
    int lo = (blockIdx.x & 7) * rs;
    int i = (blockIdx.x >> 3) * 256 + threadIdx.x;
    if (i < E) {
        int d = dst[i];
        if (d >= lo && d < lo + rs) atomicAdd(&deg[d], 1);
    }
}

__global__ void k_place_xcd(const int* __restrict__ src, const int* __restrict__ dst,
                            int* __restrict__ cursor, int* __restrict__ sidx,
                            int E, int rs) {
    int lo = (blockIdx.x & 7) * rs;
    int i = (blockIdx.x >> 3) * 256 + threadIdx.x;
    if (i < E) {
        int d = dst[i];
        if (d >= lo && d < lo + rs) {
            int pos = atomicAdd(&cursor[d], 1);
            sidx[pos] = src[i];
        }
    }
}

__global__ void k_dinv(const int* __restrict__ deg, float* __restrict__ dinv, int n) {
    int i = blockIdx.x * 256 + threadIdx.x;
    if (i < n) {
        int d = deg[i];
        dinv[i] = d > 0 ? rsqrtf((float)d) : 0.f;
    }
}

__global__ void k_blocksum(const int* __restrict__ cnt, int* __restrict__ bsum, int n) {
    __shared__ int ls[256];
    int i = blockIdx.x * 256 + threadIdx.x;
    ls[threadIdx.x] = i < n ? cnt[i] : 0;
    __syncthreads();
    for (int off = 128; off > 0; off >>= 1) {
        if (threadIdx.x < off) ls[threadIdx.x] += ls[threadIdx.x + off];
        __syncthreads();
    }
    if (threadIdx.x == 0) bsum[blockIdx.x] = ls[0];
}

__global__ void k_scanbsum(int* bsum, int nb) {
    if (threadIdx.x == 0 && blockIdx.x == 0) {
        int acc = 0;
        for (int i = 0; i < nb; ++i) { int v = bsum[i]; bsum[i] = acc; acc += v; }
    }
}

__global__ void k_scanchunk(const int* __restrict__ cnt, const int* __restrict__ bsum,
                            int* __restrict__ row_ptr, int* __restrict__ cursor,
                            int n, int E) {
    __shared__ int ls[256];
    int i = blockIdx.x * 256 + threadIdx.x;
    int v = i < n ? cnt[i] : 0;
    ls[threadIdx.x] = v;
    __syncthreads();
    for (int off = 1; off < 256; off <<= 1) {
        int t = threadIdx.x >= off ? ls[threadIdx.x - off] : 0;
        __syncthreads();
        ls[threadIdx.x] += t;
        __syncthreads();
    }
    if (i < n) {
        int ex = ls[threadIdx.x] - v + bsum[blockIdx.x];
        row_ptr[i] = ex;
        cursor[i] = ex;
    }
    if (i == n - 1) row_ptr[n] = E;
}

// ---------------- weight pack: W[k][Nw] fp32 -> Wt[Npad][128] fp16 ----------------

__global__ void k_packW(const float* __restrict__ W, __half* __restrict__ Wt,
                        int Nw, int Npad) {
    int i = blockIdx.x * 256 + threadIdx.x;
    if (i >= Npad * 128) return;
    int n = i >> 7, k = i & 127;
    Wt[i] = (n < Nw) ? __float2half(W[(size_t)k * Nw + n]) : __half(0.f);
}

// ---------------- MFMA GEMM (optional fused BN+ReLU on A) ----------------
// AMODE 0: A fp32, plain. AMODE 1: A fp16, a = relu(a*scale[c]+shift[c]).
// C[row][0..OUTW) fp16 = dinv[row] * (A'[row] @ W), K=128.

template <int CT, int OUTW, int AMODE>
__global__ __launch_bounds__(256) void k_gemm_mfma(const void* __restrict__ Ap,
                                                   const __half* __restrict__ Wt,
                                                   const float* __restrict__ scale,
                                                   const float* __restrict__ shift,
                                                   const float* __restrict__ dinv,
                                                   __half* __restrict__ C, int nrows) {
    __shared__ char lw[CT * 16 * 256];
    __shared__ float lsc[128], lsh[128];
    const int nu4 = CT * 16 * 16;
    for (int i = threadIdx.x; i < nu4; i += 256) {
        int row = i >> 4, k8 = i & 15;
        uint4 v = ((const uint4*)Wt)[i];
        *(uint4*)(lw + ((row * 256 + k8 * 16) ^ ((row & 7) << 4))) = v;
    }
    if (AMODE == 1 && threadIdx.x < 128) {
        lsc[threadIdx.x] = scale[threadIdx.x];
        lsh[threadIdx.x] = shift[threadIdx.x];
    }
    __syncthreads();

    const int lane = threadIdx.x & 63;
    const int wid = threadIdx.x >> 6;
    const int l15 = lane & 15;
    const int lg = lane >> 4;
    const int rowbase = blockIdx.x * 128 + wid * 32;

    floatx4 acc[2][CT];
#pragma unroll
    for (int r = 0; r < 2; ++r)
#pragma unroll
        for (int c = 0; c < CT; ++c) acc[r][c] = (floatx4){0.f, 0.f, 0.f, 0.f};

    for (int kk = 0; kk < 4; ++kk) {
        half8 afrag[2];
        const int c0 = kk * 32 + lg * 8;
#pragma unroll
        for (int r = 0; r < 2; ++r) {
            int row = rowbase + r * 16 + l15;
            half8 h = {0, 0, 0, 0, 0, 0, 0, 0};
            if (row < nrows) {
                if (AMODE == 0) {
                    const float* a = (const float*)Ap + (size_t)row * 128 + c0;
                    float4 v0 = *(const float4*)a;
                    float4 v1 = *(const float4*)(a + 4);
                    h[0] = (_Float16)v0.x; h[1] = (_Float16)v0.y;
                    h[2] = (_Float16)v0.z; h[3] = (_Float16)v0.w;
                    h[4] = (_Float16)v1.x; h[5] = (_Float16)v1.y;
                    h[6] = (_Float16)v1.z; h[7] = (_Float16)v1.w;
                } else {
                    uint4 raw = *(const uint4*)((const __half*)Ap + (size_t)row * 128 + c0);
                    float f[8];
                    unpack8(raw, f);
                    float4 s0 = *(const float4*)&lsc[c0];
                    float4 s1 = *(const float4*)&lsc[c0 + 4];
                    float4 t0 = *(const float4*)&lsh[c0];
                    float4 t1 = *(const float4*)&lsh[c0 + 4];
                    h[0] = (_Float16)fmaxf(f[0] * s0.x + t0.x, 0.f);
                    h[1] = (_Float16)fmaxf(f[1] * s0.y + t0.y, 0.f);
                    h[2] = (_Float16)fmaxf(f[2] * s0.z + t0.z, 0.f);
                    h[3] = (_Float16)fmaxf(f[3] * s0.w + t0.w, 0.f);
                    h[4] = (_Float16)fmaxf(f[4] * s1.x + t1.x, 0.f);
                    h[5] = (_Float16)fmaxf(f[5] * s1.y + t1.y, 0.f);
                    h[6] = (_Float16)fmaxf(f[6] * s1.z + t1.z, 0.f);
                    h[7] = (_Float16)fmaxf(f[7] * s1.w + t1.w, 0.f);
                }
            }
            afrag[r] = h;
        }
#pragma unroll
        for (int c = 0; c < CT; ++c) {
            int wrow = c * 16 + l15;
            half8 bfrag = *(const half8*)(lw + ((wrow * 256 + kk * 64 + lg * 16) ^ ((wrow & 7) << 4)));
#pragma unroll
            for (int r = 0; r < 2; ++r)
                acc[r][c] = __builtin_amdgcn_mfma_f32_16x16x32_f16(afrag[r], bfrag, acc[r][c], 0, 0, 0);
        }
    }

#pragma unroll
    for (int r = 0; r < 2; ++r) {
        int rbase = rowbase + r * 16 + lg * 4;
        float d4[4];
#pragma unroll
        for (int j = 0; j < 4; ++j)
            d4[j] = (rbase + j) < nrows ? dinv[rbase + j] : 0.f;
#pragma unroll
        for (int c = 0; c < CT; ++c) {
            int col = c * 16 + l15;
            if (OUTW != CT * 16 && col >= OUTW) continue;
#pragma unroll
            for (int j = 0; j < 4; ++j) {
                int row = rbase + j;
                if (row < nrows)
                    C[(size_t)row * OUTW + col] = __float2half(acc[r][c][j] * d4[j]);
            }
        }
    }
}

// ---------------- aggregation + fused BN stats ----------------
// 4x-unrolled gather (4 rows in flight per 16-lane group); stats reduced via
// shfl_xor across the wave's 4 groups, then a 4KB LDS pass + atomics.

__global__ __launch_bounds__(256) void k_agg128_stats(const __half* __restrict__ M,
                                                      const int* __restrict__ rp,
                                                      const int* __restrict__ sidx,
                                                      const float* __restrict__ dinv,
                                                      __half* __restrict__ Hout,
                                                      float* __restrict__ sums32,
                                                      float* __restrict__ sumsq32, int n) {
    int d = blockIdx.x * 16 + (threadIdx.x >> 4);
    int lane = threadIdx.x & 15;
    float acc[8] = {0.f, 0.f, 0.f, 0.f, 0.f, 0.f, 0.f, 0.f};
    if (d < n) {
        int beg = rp[d], end = rp[d + 1];
        int j = beg;
        for (; j + 4 <= end; j += 4) {
            int s0 = sidx[j], s1 = sidx[j + 1], s2 = sidx[j + 2], s3 = sidx[j + 3];
            uint4 v0 = *(const uint4*)(M + (size_t)s0 * 128 + lane * 8);
            uint4 v1 = *(const uint4*)(M + (size_t)s1 * 128 + lane * 8);
            uint4 v2 = *(const uint4*)(M + (size_t)s2 * 128 + lane * 8);
            uint4 v3 = *(const uint4*)(M + (size_t)s3 * 128 + lane * 8);
            float f0[8], f1[8], f2[8], f3[8];
            unpack8(v0, f0); unpack8(v1, f1); unpack8(v2, f2); unpack8(v3, f3);
#pragma unroll
            for (int i = 0; i < 8; ++i)
                acc[i] += (f0[i] + f1[i]) + (f2[i] + f3[i]);
        }
        for (; j < end; ++j) {
            int s = sidx[j];
            uint4 v = *(const uint4*)(M + (size_t)s * 128 + lane * 8);
            float f[8];
            unpack8(v, f);
#pragma unroll
            for (int i = 0; i < 8; ++i) acc[i] += f[i];
        }
        float sc = dinv[d];
#pragma unroll
        for (int i = 0; i < 8; ++i) acc[i] *= sc;
        *(uint4*)(Hout + (size_t)d * 128 + lane * 8) = pack8(acc);
    }
    // stats on scaled values
    float sq[8];
#pragma unroll
    for (int i = 0; i < 8; ++i) sq[i] = acc[i] * acc[i];
    // reduce across the wave's 4 groups (same columns, different d)
#pragma unroll
    for (int m = 16; m <= 32; m <<= 1) {
#pragma unroll
        for (int i = 0; i < 8; ++i) {
            acc[i] += __shfl_xor(acc[i], m);
            sq[i]  += __shfl_xor(sq[i], m);
        }
    }
    __shared__ float lsw[2][4][16][8];  // 4 KB
    int wid = threadIdx.x >> 6, wl = threadIdx.x & 63;
    if (wl < 16) {
#pragma unroll
        for (int i = 0; i < 8; ++i) {
            lsw[0][wid][wl][i] = acc[i];
            lsw[1][wid][wl][i] = sq[i];
        }
    }
    __syncthreads();
    if (threadIdx.x < 128) {
        int c = threadIdx.x;
        int lc = c >> 3, e = c & 7;
        float ss = 0.f, qq = 0.f;
#pragma unroll
        for (int w = 0; w < 4; ++w) {
            ss += lsw[0][w][lc][e];
            qq += lsw[1][w][lc][e];
        }
        int sh = (blockIdx.x & 31) * 128;
        atomicAdd(&sums32[sh + c], ss);
        atomicAdd(&sumsq32[sh + c], qq);
    }
}

__global__ void k_bnfinal32(const float* __restrict__ sums32, const float* __restrict__ sumsq32,
                            const float* __restrict__ g, const float* __restrict__ beta,
                            float* __restrict__ scale, float* __restrict__ shift, int nrows) {
    int c = threadIdx.x;
    float s = 0.f, q = 0.f;
    for (int k = 0; k < 32; ++k) { s += sums32[k * 128 + c]; q += sumsq32[k * 128 + c]; }
    float inv_n = 1.f / (float)nrows;
    float mu = s * inv_n;
    float var = q * inv_n - mu * mu;
    float rs = rsqrtf(var + 1e-5f);
    float sc = rs * g[c];
    scale[c] = sc;
    shift[c] = beta[c] - mu * sc;
}

// ---------------- layer-3 aggregation (4x unrolled) ----------------

__global__ void k_agg40_f16(const __half* __restrict__ M,
                            const int* __restrict__ rp,
                            const int* __restrict__ sidx,
                            const float* __restrict__ dinv,
                            const float* __restrict__ b3,
                            float* __restrict__ out, int n) {
    int i = blockIdx.x * 256 + threadIdx.x;
    if (i >= n * 5) return;
    int d = i / 5, q = i % 5;
    int beg = rp[d], end = rp[d + 1];
    float acc[8] = {0.f, 0.f, 0.f, 0.f, 0.f, 0.f, 0.f, 0.f};
    int j = beg;
    for (; j + 4 <= end; j += 4) {
        int s0 = sidx[j], s1 = sidx[j + 1], s2 = sidx[j + 2], s3 = sidx[j + 3];
        uint4 v0 = *(const uint4*)(M + (size_t)s0 * 40 + q * 8);
        uint4 v1 = *(const uint4*)(M + (size_t)s1 * 40 + q * 8);
        uint4 v2 = *(const uint4*)(M + (size_t)s2 * 40 + q * 8);
        uint4 v3 = *(const uint4*)(M + (size_t)s3 * 40 + q * 8);
        float f0[8], f1[8], f2[8], f3[8];
        unpack8(v0, f0); unpack8(v1, f1); unpack8(v2, f2); unpack8(v3, f3);
#pragma unroll
        for (int k = 0; k < 8; ++k)
            acc[k] += (f0[k] + f1[k]) + (f2[k] + f3[k]);
    }
    for (; j < end; ++j) {
        int s = sidx[j];
        uint4 v = *(const uint4*)(M + (size_t)s * 40 + q * 8);
        float f[8];
        unpack8(v, f);
#pragma unroll
        for (int k = 0; k < 8; ++k) acc[k] += f[k];
    }
    float sc = dinv[d];
    float4 b0 = *(const float4*)&b3[q * 8];
    float4 b1 = *(const float4*)&b3[q * 8 + 4];
    float4 r0, r1;
    r0.x = acc[0] * sc + b0.x; r0.y = acc[1] * sc + b0.y;
    r0.z = acc[2] * sc + b0.z; r0.w = acc[3] * sc + b0.w;
    r1.x = acc[4] * sc + b1.x; r1.y = acc[5] * sc + b1.y;
    r1.z = acc[6] * sc + b1.z; r1.w = acc[7] * sc + b1.w;
    float* o = out + (size_t)d * 40 + q * 8;
    *(float4*)o = r0;
    *(float4*)(o + 4) = r1;
}

// ---------------- launch ----------------

extern "C" void kernel_launch(void* const* d_in, const int* in_sizes, int n_in,
                              void* d_out, int out_size, void* d_ws, size_t ws_size,
                              hipStream_t stream) {
    const float* x  = (const float*)d_in[0];
    const int*   ei = (const int*)d_in[1];
    const float* W1 = (const float*)d_in[2];
    const float* g1 = (const float*)d_in[4];
    const float* be1= (const float*)d_in[5];
    const float* W2 = (const float*)d_in[6];
    const float* g2 = (const float*)d_in[8];
    const float* be2= (const float*)d_in[9];
    const float* W3 = (const float*)d_in[10];
    const float* b3 = (const float*)d_in[11];

    const int N = in_sizes[0] / 128;
    const int E = in_sizes[1] / 2;
    const int* srcv = ei;
    const int* dstv = ei + E;
    const int NB = (N + 255) / 256;
    const int RS = (N + 7) / 8;                 // per-XCD dst range
    const int EB8 = 8 * ((E + 255) / 256);      // xcd-partitioned edge grids

    __half* M    = (__half*)d_ws;                 // N*128
    __half* Hb   = M + (size_t)N * 128;           // N*128
    __half* t3   = Hb + (size_t)N * 128;          // N*40
    __half* Wt1  = t3 + (size_t)N * 40;           // 128*128
    __half* Wt2  = Wt1 + 128 * 128;
    __half* Wt3  = Wt2 + 128 * 128;               // 48*128
    float* dinv    = (float*)(Wt3 + 48 * 128);
    int*   deg     = (int*)(dinv + N);
    int*   row_ptr = deg + N;            // N+1
    int*   cursor  = row_ptr + N + 1;    // N
    int*   sidx    = cursor + N;         // E
    int*   bsum    = sidx + E;           // NB
    float* sums32  = (float*)(bsum + NB + 1); // 32*128
    float* sumsq32 = sums32 + 32 * 128;       // 32*128
    float* scale   = sumsq32 + 32 * 128;      // 128
    float* shift   = scale + 128;             // 128
    float* out     = (float*)d_out;

    const int GB = (N + 127) / 128;

    // ---- weight packs ----
    k_packW<<<(128 * 128 + 255) / 256, 256, 0, stream>>>(W1, Wt1, 128, 128);
    k_packW<<<(128 * 128 + 255) / 256, 256, 0, stream>>>(W2, Wt2, 128, 128);
    k_packW<<<(48 * 128 + 255) / 256, 256, 0, stream>>>(W3, Wt3, 40, 48);

    // ---- CSR build (XCD-partitioned counting sort) ----
    k_zeroi<<<(N + 255) / 256, 256, 0, stream>>>(deg, N);
    k_deg_xcd<<<EB8, 256, 0, stream>>>(dstv, deg, E, RS);
    k_dinv<<<(N + 255) / 256, 256, 0, stream>>>(deg, dinv, N);
    k_blocksum<<<NB, 256, 0, stream>>>(deg, bsum, N);
    k_scanbsum<<<1, 64, 0, stream>>>(bsum, NB);
    k_scanchunk<<<NB, 256, 0, stream>>>(deg, bsum, row_ptr, cursor, N, E);
    k_place_xcd<<<EB8, 256, 0, stream>>>(srcv, dstv, cursor, sidx, E, RS);

    // ---- layer 1 ----
    k_zero4<<<(2048 + 255) / 256, 256, 0, stream>>>((float4*)sums32, 2048);
    k_gemm_mfma<8, 128, 0><<<GB, 256, 0, stream>>>(x, Wt1, nullptr, nullptr, dinv, M, N);
    k_agg128_stats<<<(N + 15) / 16, 256, 0, stream>>>(M, row_ptr, sidx, dinv, Hb, sums32, sumsq32, N);
    k_bnfinal32<<<1, 128, 0, stream>>>(sums32, sumsq32, g1, be1, scale, shift, N);

    // ---- layer 2 ----
    k_gemm_mfma<8, 128, 1><<<GB, 256, 0, stream>>>(Hb, Wt2, scale, shift, dinv, M, N);
    k_zero4<<<(2048 + 255) / 256, 256, 0, stream>>>((float4*)sums32, 2048);
    k_agg128_stats<<<(N + 15) / 16, 256, 0, stream>>>(M, row_ptr, sidx, dinv, Hb, sums32, sumsq32, N);
    k_bnfinal32<<<1, 128, 0, stream>>>(sums32, sumsq32, g2, be2, scale, shift, N);

    // ---- layer 3 ----
    k_gemm_mfma<3, 40, 1><<<GB, 256, 0, stream>>>(Hb, Wt3, scale, shift, dinv, t3, N);
    k_agg40_f16<<<(N * 5 + 255) / 256, 256, 0, stream>>>(t3, row_ptr, sidx, dinv, b3, out, N);
}

// Round 8
// 240.973 us; speedup vs baseline: 1.3564x; 1.0266x over previous
//
#include <hip/hip_runtime.h>
#include <hip/hip_fp16.h>

typedef _Float16 half8 __attribute__((ext_vector_type(8)));
typedef float floatx4 __attribute__((ext_vector_type(4)));

// ---------------- helpers ----------------

__device__ __forceinline__ void unpack8(uint4 v, float* f) {
    const __half2* hp = (const __half2*)&v;
    float2 a = __half22float2(hp[0]);
    float2 b = __half22float2(hp[1]);
    float2 c = __half22float2(hp[2]);
    float2 d = __half22float2(hp[3]);
    f[0] = a.x; f[1] = a.y; f[2] = b.x; f[3] = b.y;
    f[4] = c.x; f[5] = c.y; f[6] = d.x; f[7] = d.y;
}

__device__ __forceinline__ uint4 pack8(const float* f) {
    __half2 h0 = __floats2half2_rn(f[0], f[1]);
    __half2 h1 = __floats2half2_rn(f[2], f[3]);
    __half2 h2 = __floats2half2_rn(f[4], f[5]);
    __half2 h3 = __floats2half2_rn(f[6], f[7]);
    uint4 v;
    v.x = *(const unsigned int*)&h0;
    v.y = *(const unsigned int*)&h1;
    v.z = *(const unsigned int*)&h2;
    v.w = *(const unsigned int*)&h3;
    return v;
}

__global__ void k_zeroz(int* p, int n) {
    int i = blockIdx.x * 256 + threadIdx.x;
    if (i < n) p[i] = 0;
}

// ---------------- weight pack (all three) ----------------
// W[k][Nw] fp32 -> Wt[n][k] fp16 (transposed, col-padded)

__global__ void k_packW3(const float* __restrict__ W1, const float* __restrict__ W2,
                         const float* __restrict__ W3, __half* __restrict__ Wt1,
                         __half* __restrict__ Wt2, __half* __restrict__ Wt3) {
    int i = blockIdx.x * 256 + threadIdx.x;
    if (i < 128 * 128) {
        int n = i >> 7, k = i & 127;
        Wt1[i] = __float2half(W1[(size_t)k * 128 + n]);
    } else if (i < 2 * 128 * 128) {
        int j = i - 128 * 128;
        int n = j >> 7, k = j & 127;
        Wt2[j] = __float2half(W2[(size_t)k * 128 + n]);
    } else if (i < 2 * 128 * 128 + 48 * 128) {
        int j = i - 2 * 128 * 128;
        int n = j >> 7, k = j & 127;
        Wt3[j] = (n < 40) ? __float2half(W3[(size_t)k * 40 + n]) : __half(0.f);
    }
}

// ---------------- CSR build (counting sort, XCD-range-partitioned) ----------------

__global__ void k_deg_xcd(const int* __restrict__ dst, int* __restrict__ deg,
                          int E, int rs) {
    int lo = (blockIdx.x & 7) * rs;
    int i = (blockIdx.x >> 3) * 256 + threadIdx.x;
    if (i < E) {
        int d = dst[i];
        if (d >= lo && d < lo + rs) atomicAdd(&deg[d], 1);
    }
}

__global__ void k_place_xcd(const int* __restrict__ src, const int* __restrict__ dst,
                            int* __restrict__ cursor, int* __restrict__ sidx,
                            int E, int rs) {
    int lo = (blockIdx.x & 7) * rs;
    int i = (blockIdx.x >> 3) * 256 + threadIdx.x;
    if (i < E) {
        int d = dst[i];
        if (d >= lo && d < lo + rs) {
            int pos = atomicAdd(&cursor[d], 1);
            sidx[pos] = src[i];
        }
    }
}

// single block: per-256-chunk sums of deg + exclusive scan -> bsum[chunk]
__global__ __launch_bounds__(256) void k_chunkscan(const int* __restrict__ deg,
                                                   int* __restrict__ bsum, int n) {
    __shared__ int ls[256];
    int t = threadIdx.x;
    int s = 0;
    int base = t * 256;
    for (int k = 0; k < 256; ++k) {
        int idx = base + k;
        if (idx < n) s += deg[idx];
    }
    ls[t] = s;
    __syncthreads();
    for (int off = 1; off < 256; off <<= 1) {
        int v = t >= off ? ls[t - off] : 0;
        __syncthreads();
        ls[t] += v;
        __syncthreads();
    }
    bsum[t] = ls[t] - s;  // exclusive
}

__global__ void k_scanchunk(const int* __restrict__ cnt, const int* __restrict__ bsum,
                            int* __restrict__ row_ptr, int* __restrict__ cursor,
                            float* __restrict__ dinv, int n, int E) {
    __shared__ int ls[256];
    int i = blockIdx.x * 256 + threadIdx.x;
    int v = i < n ? cnt[i] : 0;
    ls[threadIdx.x] = v;
    __syncthreads();
    for (int off = 1; off < 256; off <<= 1) {
        int t = threadIdx.x >= off ? ls[threadIdx.x - off] : 0;
        __syncthreads();
        ls[threadIdx.x] += t;
        __syncthreads();
    }
    if (i < n) {
        int ex = ls[threadIdx.x] - v + bsum[blockIdx.x];
        row_ptr[i] = ex;
        cursor[i] = ex;
        dinv[i] = v > 0 ? rsqrtf((float)v) : 0.f;
    }
    if (i == n - 1) row_ptr[n] = E;
}

// ---------------- MFMA GEMM (fused BN+ReLU on A via in-kernel bnfinal) ----------------
// AMODE 0: A fp32, plain. AMODE 1: A fp16; scale/shift computed per block from
// 32-shadow stats buffers + g/beta. C[row][0..VALID) fp16 at row stride STRIDE.

template <int CT, int STRIDE, int VALID, int AMODE>
__global__ __launch_bounds__(256) void k_gemm_mfma(const void* __restrict__ Ap,
                                                   const __half* __restrict__ Wt,
                                                   const float* __restrict__ sums32,
                                                   const float* __restrict__ sumsq32,
                                                   const float* __restrict__ g,
                                                   const float* __restrict__ beta,
                                                   const float* __restrict__ dinv,
                                                   __half* __restrict__ C, int nrows) {
    __shared__ char lw[CT * 16 * 256];
    __shared__ float lsc[128], lsh[128];
    const int nu4 = CT * 16 * 16;
    for (int i = threadIdx.x; i < nu4; i += 256) {
        int row = i >> 4, k8 = i & 15;
        uint4 v = ((const uint4*)Wt)[i];
        *(uint4*)(lw + ((row * 256 + k8 * 16) ^ ((row & 7) << 4))) = v;
    }
    if (AMODE == 1 && threadIdx.x < 128) {
        int c = threadIdx.x;
        float s = 0.f, q = 0.f;
        for (int k2 = 0; k2 < 32; ++k2) {
            s += sums32[k2 * 128 + c];
            q += sumsq32[k2 * 128 + c];
        }
        float inv_n = 1.f / (float)nrows;
        float mu = s * inv_n;
        float var = q * inv_n - mu * mu;
        float rs = rsqrtf(var + 1e-5f);
        float sc = rs * g[c];
        lsc[c] = sc;
        lsh[c] = beta[c] - mu * sc;
    }
    __syncthreads();

    const int lane = threadIdx.x & 63;
    const int wid = threadIdx.x >> 6;
    const int l15 = lane & 15;
    const int lg = lane >> 4;
    const int rowbase = blockIdx.x * 128 + wid * 32;

    floatx4 acc[2][CT];
#pragma unroll
    for (int r = 0; r < 2; ++r)
#pragma unroll
        for (int c = 0; c < CT; ++c) acc[r][c] = (floatx4){0.f, 0.f, 0.f, 0.f};

    for (int kk = 0; kk < 4; ++kk) {
        half8 afrag[2];
        const int c0 = kk * 32 + lg * 8;
#pragma unroll
        for (int r = 0; r < 2; ++r) {
            int row = rowbase + r * 16 + l15;
            half8 h = {0, 0, 0, 0, 0, 0, 0, 0};
            if (row < nrows) {
                if (AMODE == 0) {
                    const float* a = (const float*)Ap + (size_t)row * 128 + c0;
                    float4 v0 = *(const float4*)a;
                    float4 v1 = *(const float4*)(a + 4);
                    h[0] = (_Float16)v0.x; h[1] = (_Float16)v0.y;
                    h[2] = (_Float16)v0.z; h[3] = (_Float16)v0.w;
                    h[4] = (_Float16)v1.x; h[5] = (_Float16)v1.y;
                    h[6] = (_Float16)v1.z; h[7] = (_Float16)v1.w;
                } else {
                    uint4 raw = *(const uint4*)((const __half*)Ap + (size_t)row * 128 + c0);
                    float f[8];
                    unpack8(raw, f);
                    float4 s0 = *(const float4*)&lsc[c0];
                    float4 s1 = *(const float4*)&lsc[c0 + 4];
                    float4 t0 = *(const float4*)&lsh[c0];
                    float4 t1 = *(const float4*)&lsh[c0 + 4];
                    h[0] = (_Float16)fmaxf(f[0] * s0.x + t0.x, 0.f);
                    h[1] = (_Float16)fmaxf(f[1] * s0.y + t0.y, 0.f);
                    h[2] = (_Float16)fmaxf(f[2] * s0.z + t0.z, 0.f);
                    h[3] = (_Float16)fmaxf(f[3] * s0.w + t0.w, 0.f);
                    h[4] = (_Float16)fmaxf(f[4] * s1.x + t1.x, 0.f);
                    h[5] = (_Float16)fmaxf(f[5] * s1.y + t1.y, 0.f);
                    h[6] = (_Float16)fmaxf(f[6] * s1.z + t1.z, 0.f);
                    h[7] = (_Float16)fmaxf(f[7] * s1.w + t1.w, 0.f);
                }
            }
            afrag[r] = h;
        }
#pragma unroll
        for (int c = 0; c < CT; ++c) {
            int wrow = c * 16 + l15;
            half8 bfrag = *(const half8*)(lw + ((wrow * 256 + kk * 64 + lg * 16) ^ ((wrow & 7) << 4)));
#pragma unroll
            for (int r = 0; r < 2; ++r)
                acc[r][c] = __builtin_amdgcn_mfma_f32_16x16x32_f16(afrag[r], bfrag, acc[r][c], 0, 0, 0);
        }
    }

#pragma unroll
    for (int r = 0; r < 2; ++r) {
        int rbase = rowbase + r * 16 + lg * 4;
        float d4[4];
#pragma unroll
        for (int j = 0; j < 4; ++j)
            d4[j] = (rbase + j) < nrows ? dinv[rbase + j] : 0.f;
#pragma unroll
        for (int c = 0; c < CT; ++c) {
            int col = c * 16 + l15;
            if (VALID != CT * 16 && col >= VALID) continue;
#pragma unroll
            for (int j = 0; j < 4; ++j) {
                int row = rbase + j;
                if (row < nrows)
                    C[(size_t)row * STRIDE + col] = __float2half(acc[r][c][j] * d4[j]);
            }
        }
    }
}

// ---------------- aggregation + fused BN stats ----------------

__global__ __launch_bounds__(256) void k_agg128_stats(const __half* __restrict__ M,
                                                      const int* __restrict__ rp,
                                                      const int* __restrict__ sidx,
                                                      const float* __restrict__ dinv,
                                                      __half* __restrict__ Hout,
                                                      float* __restrict__ sums32,
                                                      float* __restrict__ sumsq32, int n) {
    int d = blockIdx.x * 16 + (threadIdx.x >> 4);
    int lane = threadIdx.x & 15;
    float acc[8] = {0.f, 0.f, 0.f, 0.f, 0.f, 0.f, 0.f, 0.f};
    if (d < n) {
        int beg = rp[d], end = rp[d + 1];
        int j = beg;
        for (; j + 4 <= end; j += 4) {
            int s0 = sidx[j], s1 = sidx[j + 1], s2 = sidx[j + 2], s3 = sidx[j + 3];
            uint4 v0 = *(const uint4*)(M + (size_t)s0 * 128 + lane * 8);
            uint4 v1 = *(const uint4*)(M + (size_t)s1 * 128 + lane * 8);
            uint4 v2 = *(const uint4*)(M + (size_t)s2 * 128 + lane * 8);
            uint4 v3 = *(const uint4*)(M + (size_t)s3 * 128 + lane * 8);
            float f0[8], f1[8], f2[8], f3[8];
            unpack8(v0, f0); unpack8(v1, f1); unpack8(v2, f2); unpack8(v3, f3);
#pragma unroll
            for (int i = 0; i < 8; ++i)
                acc[i] += (f0[i] + f1[i]) + (f2[i] + f3[i]);
        }
        for (; j < end; ++j) {
            int s = sidx[j];
            uint4 v = *(const uint4*)(M + (size_t)s * 128 + lane * 8);
            float f[8];
            unpack8(v, f);
#pragma unroll
            for (int i = 0; i < 8; ++i) acc[i] += f[i];
        }
        float sc = dinv[d];
#pragma unroll
        for (int i = 0; i < 8; ++i) acc[i] *= sc;
        *(uint4*)(Hout + (size_t)d * 128 + lane * 8) = pack8(acc);
    }
    float sq[8];
#pragma unroll
    for (int i = 0; i < 8; ++i) sq[i] = acc[i] * acc[i];
#pragma unroll
    for (int m = 16; m <= 32; m <<= 1) {
#pragma unroll
        for (int i = 0; i < 8; ++i) {
            acc[i] += __shfl_xor(acc[i], m);
            sq[i]  += __shfl_xor(sq[i], m);
        }
    }
    __shared__ float lsw[2][4][16][8];  // 4 KB
    int wid = threadIdx.x >> 6, wl = threadIdx.x & 63;
    if (wl < 16) {
#pragma unroll
        for (int i = 0; i < 8; ++i) {
            lsw[0][wid][wl][i] = acc[i];
            lsw[1][wid][wl][i] = sq[i];
        }
    }
    __syncthreads();
    if (threadIdx.x < 128) {
        int c = threadIdx.x;
        int lc = c >> 3, e = c & 7;
        float ss = 0.f, qq = 0.f;
#pragma unroll
        for (int w = 0; w < 4; ++w) {
            ss += lsw[0][w][lc][e];
            qq += lsw[1][w][lc][e];
        }
        int sh = (blockIdx.x & 31) * 128;
        atomicAdd(&sums32[sh + c], ss);
        atomicAdd(&sumsq32[sh + c], qq);
    }
}

// ---------------- layer-3 aggregation (t3 row stride 64) ----------------

__global__ void k_agg40_f16(const __half* __restrict__ M,
                            const int* __restrict__ rp,
                            const int* __restrict__ sidx,
                            const float* __restrict__ dinv,
                            const float* __restrict__ b3,
                            float* __restrict__ out, int n) {
    int i = blockIdx.x * 256 + threadIdx.x;
    if (i >= n * 5) return;
    int d = i / 5, q = i % 5;
    int beg = rp[d], end = rp[d + 1];
    float acc[8] = {0.f, 0.f, 0.f, 0.f, 0.f, 0.f, 0.f, 0.f};
    int j = beg;
    for (; j + 4 <= end; j += 4) {
        int s0 = sidx[j], s1 = sidx[j + 1], s2 = sidx[j + 2], s3 = sidx[j + 3];
        uint4 v0 = *(const uint4*)(M + (size_t)s0 * 64 + q * 8);
        uint4 v1 = *(const uint4*)(M + (size_t)s1 * 64 + q * 8);
        uint4 v2 = *(const uint4*)(M + (size_t)s2 * 64 + q * 8);
        uint4 v3 = *(const uint4*)(M + (size_t)s3 * 64 + q * 8);
        float f0[8], f1[8], f2[8], f3[8];
        unpack8(v0, f0); unpack8(v1, f1); unpack8(v2, f2); unpack8(v3, f3);
#pragma unroll
        for (int k = 0; k < 8; ++k)
            acc[k] += (f0[k] + f1[k]) + (f2[k] + f3[k]);
    }
    for (; j < end; ++j) {
        int s = sidx[j];
        uint4 v = *(const uint4*)(M + (size_t)s * 64 + q * 8);
        float f[8];
        unpack8(v, f);
#pragma unroll
        for (int k = 0; k < 8; ++k) acc[k] += f[k];
    }
    float sc = dinv[d];
    float4 b0 = *(const float4*)&b3[q * 8];
    float4 b1 = *(const float4*)&b3[q * 8 + 4];
    float4 r0, r1;
    r0.x = acc[0] * sc + b0.x; r0.y = acc[1] * sc + b0.y;
    r0.z = acc[2] * sc + b0.z; r0.w = acc[3] * sc + b0.w;
    r1.x = acc[4] * sc + b1.x; r1.y = acc[5] * sc + b1.y;
    r1.z = acc[6] * sc + b1.z; r1.w = acc[7] * sc + b1.w;
    float* o = out + (size_t)d * 40 + q * 8;
    *(float4*)o = r0;
    *(float4*)(o + 4) = r1;
}

// ---------------- launch ----------------

extern "C" void kernel_launch(void* const* d_in, const int* in_sizes, int n_in,
                              void* d_out, int out_size, void* d_ws, size_t ws_size,
                              hipStream_t stream) {
    const float* x  = (const float*)d_in[0];
    const int*   ei = (const int*)d_in[1];
    const float* W1 = (const float*)d_in[2];
    const float* g1 = (const float*)d_in[4];
    const float* be1= (const float*)d_in[5];
    const float* W2 = (const float*)d_in[6];
    const float* g2 = (const float*)d_in[8];
    const float* be2= (const float*)d_in[9];
    const float* W3 = (const float*)d_in[10];
    const float* b3 = (const float*)d_in[11];

    const int N = in_sizes[0] / 128;
    const int E = in_sizes[1] / 2;
    const int* srcv = ei;
    const int* dstv = ei + E;
    const int NB = (N + 255) / 256;
    const int RS = (N + 7) / 8;
    const int EB8 = 8 * ((E + 255) / 256);

    __half* M    = (__half*)d_ws;                 // N*128
    __half* Hb   = M + (size_t)N * 128;           // N*128
    __half* t3   = Hb + (size_t)N * 128;          // N*64 (padded)
    __half* Wt1  = t3 + (size_t)N * 64;           // 128*128
    __half* Wt2  = Wt1 + 128 * 128;
    __half* Wt3  = Wt2 + 128 * 128;               // 48*128
    float* dinv    = (float*)(Wt3 + 48 * 128);
    // contiguous zero block: deg + 4 stats buffers
    int*   deg     = (int*)(dinv + N);            // N
    float* sumsA   = (float*)(deg + N);           // 32*128
    float* sumsqA  = sumsA + 32 * 128;
    float* sumsB   = sumsqA + 32 * 128;
    float* sumsqB  = sumsB + 32 * 128;
    int*   row_ptr = (int*)(sumsqB + 32 * 128);   // N+1
    int*   cursor  = row_ptr + N + 1;             // N
    int*   sidx    = cursor + N;                  // E
    int*   bsum    = sidx + E;                    // 256
    float* out     = (float*)d_out;

    const int GB = (N + 127) / 128;
    const int ZN = N + 4 * 32 * 128;              // deg + stats, all 4-byte

    // ---- setup: pack weights, zero, CSR build ----
    k_packW3<<<(2 * 128 * 128 + 48 * 128 + 255) / 256, 256, 0, stream>>>(W1, W2, W3, Wt1, Wt2, Wt3);
    k_zeroz<<<(ZN + 255) / 256, 256, 0, stream>>>(deg, ZN);
    k_deg_xcd<<<EB8, 256, 0, stream>>>(dstv, deg, E, RS);
    k_chunkscan<<<1, 256, 0, stream>>>(deg, bsum, N);
    k_scanchunk<<<NB, 256, 0, stream>>>(deg, bsum, row_ptr, cursor, dinv, N, E);
    k_place_xcd<<<EB8, 256, 0, stream>>>(srcv, dstv, cursor, sidx, E, RS);

    // ---- layer 1 ----
    k_gemm_mfma<8, 128, 128, 0><<<GB, 256, 0, stream>>>(x, Wt1, nullptr, nullptr, nullptr, nullptr, dinv, M, N);
    k_agg128_stats<<<(N + 15) / 16, 256, 0, stream>>>(M, row_ptr, sidx, dinv, Hb, sumsA, sumsqA, N);

    // ---- layer 2 (BN1 fused into GEMM) ----
    k_gemm_mfma<8, 128, 128, 1><<<GB, 256, 0, stream>>>(Hb, Wt2, sumsA, sumsqA, g1, be1, dinv, M, N);
    k_agg128_stats<<<(N + 15) / 16, 256, 0, stream>>>(M, row_ptr, sidx, dinv, Hb, sumsB, sumsqB, N);

    // ---- layer 3 (BN2 fused into GEMM, t3 padded to stride 64) ----
    k_gemm_mfma<3, 64, 40, 1><<<GB, 256, 0, stream>>>(Hb, Wt3, sumsB, sumsqB, g2, be2, dinv, t3, N);
    k_agg40_f16<<<(N * 5 + 255) / 256, 256, 0, stream>>>(t3, row_ptr, sidx, dinv, b3, out, N);
}

// Round 9
// 228.250 us; speedup vs baseline: 1.4320x; 1.0557x over previous
//
#include <hip/hip_runtime.h>
#include <hip/hip_fp16.h>

typedef _Float16 half8 __attribute__((ext_vector_type(8)));
typedef float floatx4 __attribute__((ext_vector_type(4)));

// ---------------- helpers ----------------

__device__ __forceinline__ void unpack8(uint4 v, float* f) {
    const __half2* hp = (const __half2*)&v;
    float2 a = __half22float2(hp[0]);
    float2 b = __half22float2(hp[1]);
    float2 c = __half22float2(hp[2]);
    float2 d = __half22float2(hp[3]);
    f[0] = a.x; f[1] = a.y; f[2] = b.x; f[3] = b.y;
    f[4] = c.x; f[5] = c.y; f[6] = d.x; f[7] = d.y;
}

__device__ __forceinline__ uint4 pack8(const float* f) {
    __half2 h0 = __floats2half2_rn(f[0], f[1]);
    __half2 h1 = __floats2half2_rn(f[2], f[3]);
    __half2 h2 = __floats2half2_rn(f[4], f[5]);
    __half2 h3 = __floats2half2_rn(f[6], f[7]);
    uint4 v;
    v.x = *(const unsigned int*)&h0;
    v.y = *(const unsigned int*)&h1;
    v.z = *(const unsigned int*)&h2;
    v.w = *(const unsigned int*)&h3;
    return v;
}

__global__ void k_zeroz(int* p, int n) {
    int i = blockIdx.x * 256 + threadIdx.x;
    if (i < n) p[i] = 0;
}

// ---------------- weight pack (all three) ----------------

__global__ void k_packW3(const float* __restrict__ W1, const float* __restrict__ W2,
                         const float* __restrict__ W3, __half* __restrict__ Wt1,
                         __half* __restrict__ Wt2, __half* __restrict__ Wt3) {
    int i = blockIdx.x * 256 + threadIdx.x;
    if (i < 128 * 128) {
        int n = i >> 7, k = i & 127;
        Wt1[i] = __float2half(W1[(size_t)k * 128 + n]);
    } else if (i < 2 * 128 * 128) {
        int j = i - 128 * 128;
        int n = j >> 7, k = j & 127;
        Wt2[j] = __float2half(W2[(size_t)k * 128 + n]);
    } else if (i < 2 * 128 * 128 + 48 * 128) {
        int j = i - 2 * 128 * 128;
        int n = j >> 7, k = j & 127;
        Wt3[j] = (n < 40) ? __float2half(W3[(size_t)k * 40 + n]) : __half(0.f);
    }
}

// ---------------- CSR build (counting sort, XCD-range-partitioned) ----------------

__global__ void k_deg_xcd(const int* __restrict__ dst, int* __restrict__ deg,
                          int E, int rs) {
    int lo = (blockIdx.x & 7) * rs;
    int i = (blockIdx.x >> 3) * 256 + threadIdx.x;
    if (i < E) {
        int d = dst[i];
        if (d >= lo && d < lo + rs) atomicAdd(&deg[d], 1);
    }
}

__global__ void k_place_xcd(const int* __restrict__ src, const int* __restrict__ dst,
                            int* __restrict__ cursor, unsigned short* __restrict__ sidx,
                            int E, int rs) {
    int lo = (blockIdx.x & 7) * rs;
    int i = (blockIdx.x >> 3) * 256 + threadIdx.x;
    if (i < E) {
        int d = dst[i];
        if (d >= lo && d < lo + rs) {
            int pos = atomicAdd(&cursor[d], 1);
            sidx[pos] = (unsigned short)src[i];
        }
    }
}

__global__ __launch_bounds__(256) void k_chunkscan(const int* __restrict__ deg,
                                                   int* __restrict__ bsum, int n) {
    __shared__ int ls[256];
    int t = threadIdx.x;
    int s = 0;
    int base = t * 256;
    for (int k = 0; k < 256; ++k) {
        int idx = base + k;
        if (idx < n) s += deg[idx];
    }
    ls[t] = s;
    __syncthreads();
    for (int off = 1; off < 256; off <<= 1) {
        int v = t >= off ? ls[t - off] : 0;
        __syncthreads();
        ls[t] += v;
        __syncthreads();
    }
    bsum[t] = ls[t] - s;  // exclusive
}

__global__ void k_scanchunk(const int* __restrict__ cnt, const int* __restrict__ bsum,
                            int* __restrict__ row_ptr, int* __restrict__ cursor,
                            float* __restrict__ dinv, int n, int E) {
    __shared__ int ls[256];
    int i = blockIdx.x * 256 + threadIdx.x;
    int v = i < n ? cnt[i] : 0;
    ls[threadIdx.x] = v;
    __syncthreads();
    for (int off = 1; off < 256; off <<= 1) {
        int t = threadIdx.x >= off ? ls[threadIdx.x - off] : 0;
        __syncthreads();
        ls[threadIdx.x] += t;
        __syncthreads();
    }
    if (i < n) {
        int ex = ls[threadIdx.x] - v + bsum[blockIdx.x];
        row_ptr[i] = ex;
        cursor[i] = ex;
        dinv[i] = v > 0 ? rsqrtf((float)v) : 0.f;
    }
    if (i == n - 1) row_ptr[n] = E;
}

// ---------------- MFMA GEMM v2 ----------------
// CSPLIT column-blocks per row-block (grid = rowblocks*CSPLIT). Per block:
// CT*16 output cols, 128 rows. Upfront kk-unrolled A loads (MLP), LDS-
// transposed epilogue (CSPLIT==2) for coalesced uint4 C stores.
// AMODE 0: A fp32 plain. AMODE 1: A fp16, a=relu(a*scale+shift) (BN fused).

template <int CT, int STRIDE, int VALID, int AMODE, int CSPLIT>
__global__ __launch_bounds__(256) void k_gemm_mfma(const void* __restrict__ Ap,
                                                   const __half* __restrict__ Wt,
                                                   const float* __restrict__ sums32,
                                                   const float* __restrict__ sumsq32,
                                                   const float* __restrict__ g,
                                                   const float* __restrict__ beta,
                                                   const float* __restrict__ dinv,
                                                   __half* __restrict__ C, int nrows) {
    __shared__ char lw[CT * 16 * 256];
    __shared__ float lsc[128], lsh[128];
    const int rowblk = (CSPLIT == 2) ? (blockIdx.x >> 1) : blockIdx.x;
    const int colblk = (CSPLIT == 2) ? (blockIdx.x & 1) : 0;

    const int nu4 = CT * 16 * 16;
    for (int i = threadIdx.x; i < nu4; i += 256) {
        int row = i >> 4, k8 = i & 15;
        uint4 v = ((const uint4*)Wt)[(colblk * CT * 16 + row) * 16 + k8];
        *(uint4*)(lw + ((row * 256 + k8 * 16) ^ ((row & 7) << 4))) = v;
    }
    if (AMODE == 1 && threadIdx.x < 128) {
        int c = threadIdx.x;
        float s = 0.f, q = 0.f;
        for (int k2 = 0; k2 < 32; ++k2) {
            s += sums32[k2 * 128 + c];
            q += sumsq32[k2 * 128 + c];
        }
        float inv_n = 1.f / (float)nrows;
        float mu = s * inv_n;
        float var = q * inv_n - mu * mu;
        float rs = rsqrtf(var + 1e-5f);
        float sc = rs * g[c];
        lsc[c] = sc;
        lsh[c] = beta[c] - mu * sc;
    }
    __syncthreads();

    const int lane = threadIdx.x & 63;
    const int wid = threadIdx.x >> 6;
    const int l15 = lane & 15;
    const int lg = lane >> 4;
    const int rowbase = rowblk * 128 + wid * 32;

    // upfront A loads: all kk, both row-tiles -> max loads in flight
    half8 a2[2][4];
#pragma unroll
    for (int r = 0; r < 2; ++r) {
        int row = rowbase + r * 16 + l15;
        bool ok = row < nrows;
#pragma unroll
        for (int kk = 0; kk < 4; ++kk) {
            const int c0 = kk * 32 + lg * 8;
            half8 h = {0, 0, 0, 0, 0, 0, 0, 0};
            if (ok) {
                if (AMODE == 0) {
                    const float* a = (const float*)Ap + (size_t)row * 128 + c0;
                    float4 v0 = *(const float4*)a;
                    float4 v1 = *(const float4*)(a + 4);
                    h[0] = (_Float16)v0.x; h[1] = (_Float16)v0.y;
                    h[2] = (_Float16)v0.z; h[3] = (_Float16)v0.w;
                    h[4] = (_Float16)v1.x; h[5] = (_Float16)v1.y;
                    h[6] = (_Float16)v1.z; h[7] = (_Float16)v1.w;
                } else {
                    uint4 raw = *(const uint4*)((const __half*)Ap + (size_t)row * 128 + c0);
                    float f[8];
                    unpack8(raw, f);
                    float4 s0 = *(const float4*)&lsc[c0];
                    float4 s1 = *(const float4*)&lsc[c0 + 4];
                    float4 t0 = *(const float4*)&lsh[c0];
                    float4 t1 = *(const float4*)&lsh[c0 + 4];
                    h[0] = (_Float16)fmaxf(f[0] * s0.x + t0.x, 0.f);
                    h[1] = (_Float16)fmaxf(f[1] * s0.y + t0.y, 0.f);
                    h[2] = (_Float16)fmaxf(f[2] * s0.z + t0.z, 0.f);
                    h[3] = (_Float16)fmaxf(f[3] * s0.w + t0.w, 0.f);
                    h[4] = (_Float16)fmaxf(f[4] * s1.x + t1.x, 0.f);
                    h[5] = (_Float16)fmaxf(f[5] * s1.y + t1.y, 0.f);
                    h[6] = (_Float16)fmaxf(f[6] * s1.z + t1.z, 0.f);
                    h[7] = (_Float16)fmaxf(f[7] * s1.w + t1.w, 0.f);
                }
            }
            a2[r][kk] = h;
        }
    }

    floatx4 acc[2][CT];
#pragma unroll
    for (int r = 0; r < 2; ++r)
#pragma unroll
        for (int c = 0; c < CT; ++c) acc[r][c] = (floatx4){0.f, 0.f, 0.f, 0.f};

#pragma unroll
    for (int kk = 0; kk < 4; ++kk) {
#pragma unroll
        for (int c = 0; c < CT; ++c) {
            int wrow = c * 16 + l15;
            half8 bfrag = *(const half8*)(lw + ((wrow * 256 + kk * 64 + lg * 16) ^ ((wrow & 7) << 4)));
#pragma unroll
            for (int r = 0; r < 2; ++r)
                acc[r][c] = __builtin_amdgcn_mfma_f32_16x16x32_f16(a2[r][kk], bfrag, acc[r][c], 0, 0, 0);
        }
    }

    if (CSPLIT == 2) {
        // LDS-transposed epilogue -> coalesced uint4 stores. Reuse lw (16 KB).
        __syncthreads();
        __half* ct = (__half*)lw;  // [128][64], col xor'd by ((lrow>>2)&1)<<5
#pragma unroll
        for (int r = 0; r < 2; ++r) {
            int lr0 = wid * 32 + r * 16 + lg * 4;
            float d4[4];
#pragma unroll
            for (int j = 0; j < 4; ++j) {
                int row = rowblk * 128 + lr0 + j;
                d4[j] = row < nrows ? dinv[row] : 0.f;
            }
#pragma unroll
            for (int c = 0; c < CT; ++c) {
                int col = c * 16 + l15;
#pragma unroll
                for (int j = 0; j < 4; ++j) {
                    int lrow = lr0 + j;
                    int cc = col ^ (((lrow >> 2) & 1) << 5);
                    ct[lrow * 64 + cc] = __float2half(acc[r][c][j] * d4[j]);
                }
            }
        }
        __syncthreads();
        for (int i = threadIdx.x; i < 128 * 8; i += 256) {
            int lrow = i >> 3, u = i & 7;
            int row = rowblk * 128 + lrow;
            if (row < nrows) {
                int cc = (u * 8) ^ (((lrow >> 2) & 1) << 5);
                uint4 v = *(const uint4*)&ct[lrow * 64 + cc];
                *(uint4*)(&C[(size_t)row * STRIDE + colblk * 64 + u * 8]) = v;
            }
        }
    } else {
#pragma unroll
        for (int r = 0; r < 2; ++r) {
            int rbase = rowbase + r * 16 + lg * 4;
            float d4[4];
#pragma unroll
            for (int j = 0; j < 4; ++j)
                d4[j] = (rbase + j) < nrows ? dinv[rbase + j] : 0.f;
#pragma unroll
            for (int c = 0; c < CT; ++c) {
                int col = c * 16 + l15;
                if (VALID != CT * 16 && col >= VALID) continue;
#pragma unroll
                for (int j = 0; j < 4; ++j) {
                    int row = rbase + j;
                    if (row < nrows)
                        C[(size_t)row * STRIDE + col] = __float2half(acc[r][c][j] * d4[j]);
                }
            }
        }
    }
}

// ---------------- aggregation + fused BN stats ----------------

__global__ __launch_bounds__(256) void k_agg128_stats(const __half* __restrict__ M,
                                                      const int* __restrict__ rp,
                                                      const unsigned short* __restrict__ sidx,
                                                      const float* __restrict__ dinv,
                                                      __half* __restrict__ Hout,
                                                      float* __restrict__ sums32,
                                                      float* __restrict__ sumsq32, int n) {
    int d = blockIdx.x * 16 + (threadIdx.x >> 4);
    int lane = threadIdx.x & 15;
    float acc[8] = {0.f, 0.f, 0.f, 0.f, 0.f, 0.f, 0.f, 0.f};
    if (d < n) {
        int beg = rp[d], end = rp[d + 1];
        int j = beg;
        for (; j + 4 <= end; j += 4) {
            int s0 = sidx[j], s1 = sidx[j + 1], s2 = sidx[j + 2], s3 = sidx[j + 3];
            uint4 v0 = *(const uint4*)(M + (size_t)s0 * 128 + lane * 8);
            uint4 v1 = *(const uint4*)(M + (size_t)s1 * 128 + lane * 8);
            uint4 v2 = *(const uint4*)(M + (size_t)s2 * 128 + lane * 8);
            uint4 v3 = *(const uint4*)(M + (size_t)s3 * 128 + lane * 8);
            float f0[8], f1[8], f2[8], f3[8];
            unpack8(v0, f0); unpack8(v1, f1); unpack8(v2, f2); unpack8(v3, f3);
#pragma unroll
            for (int i = 0; i < 8; ++i)
                acc[i] += (f0[i] + f1[i]) + (f2[i] + f3[i]);
        }
        for (; j < end; ++j) {
            int s = sidx[j];
            uint4 v = *(const uint4*)(M + (size_t)s * 128 + lane * 8);
            float f[8];
            unpack8(v, f);
#pragma unroll
            for (int i = 0; i < 8; ++i) acc[i] += f[i];
        }
        float sc = dinv[d];
#pragma unroll
        for (int i = 0; i < 8; ++i) acc[i] *= sc;
        *(uint4*)(Hout + (size_t)d * 128 + lane * 8) = pack8(acc);
    }
    float sq[8];
#pragma unroll
    for (int i = 0; i < 8; ++i) sq[i] = acc[i] * acc[i];
#pragma unroll
    for (int m = 16; m <= 32; m <<= 1) {
#pragma unroll
        for (int i = 0; i < 8; ++i) {
            acc[i] += __shfl_xor(acc[i], m);
            sq[i]  += __shfl_xor(sq[i], m);
        }
    }
    __shared__ float lsw[2][4][16][8];  // 4 KB
    int wid = threadIdx.x >> 6, wl = threadIdx.x & 63;
    if (wl < 16) {
#pragma unroll
        for (int i = 0; i < 8; ++i) {
            lsw[0][wid][wl][i] = acc[i];
            lsw[1][wid][wl][i] = sq[i];
        }
    }
    __syncthreads();
    if (threadIdx.x < 128) {
        int c = threadIdx.x;
        int lc = c >> 3, e = c & 7;
        float ss = 0.f, qq = 0.f;
#pragma unroll
        for (int w = 0; w < 4; ++w) {
            ss += lsw[0][w][lc][e];
            qq += lsw[1][w][lc][e];
        }
        int sh = (blockIdx.x & 31) * 128;
        atomicAdd(&sums32[sh + c], ss);
        atomicAdd(&sumsq32[sh + c], qq);
    }
}

// ---------------- layer-3 aggregation (t3 row stride 64) ----------------

__global__ void k_agg40_f16(const __half* __restrict__ M,
                            const int* __restrict__ rp,
                            const unsigned short* __restrict__ sidx,
                            const float* __restrict__ dinv,
                            const float* __restrict__ b3,
                            float* __restrict__ out, int n) {
    int i = blockIdx.x * 256 + threadIdx.x;
    if (i >= n * 5) return;
    int d = i / 5, q = i % 5;
    int beg = rp[d], end = rp[d + 1];
    float acc[8] = {0.f, 0.f, 0.f, 0.f, 0.f, 0.f, 0.f, 0.f};
    int j = beg;
    for (; j + 4 <= end; j += 4) {
        int s0 = sidx[j], s1 = sidx[j + 1], s2 = sidx[j + 2], s3 = sidx[j + 3];
        uint4 v0 = *(const uint4*)(M + (size_t)s0 * 64 + q * 8);
        uint4 v1 = *(const uint4*)(M + (size_t)s1 * 64 + q * 8);
        uint4 v2 = *(const uint4*)(M + (size_t)s2 * 64 + q * 8);
        uint4 v3 = *(const uint4*)(M + (size_t)s3 * 64 + q * 8);
        float f0[8], f1[8], f2[8], f3[8];
        unpack8(v0, f0); unpack8(v1, f1); unpack8(v2, f2); unpack8(v3, f3);
#pragma unroll
        for (int k = 0; k < 8; ++k)
            acc[k] += (f0[k] + f1[k]) + (f2[k] + f3[k]);
    }
    for (; j < end; ++j) {
        int s = sidx[j];
        uint4 v = *(const uint4*)(M + (size_t)s * 64 + q * 8);
        float f[8];
        unpack8(v, f);
#pragma unroll
        for (int k = 0; k < 8; ++k) acc[k] += f[k];
    }
    float sc = dinv[d];
    float4 b0 = *(const float4*)&b3[q * 8];
    float4 b1 = *(const float4*)&b3[q * 8 + 4];
    float4 r0, r1;
    r0.x = acc[0] * sc + b0.x; r0.y = acc[1] * sc + b0.y;
    r0.z = acc[2] * sc + b0.z; r0.w = acc[3] * sc + b0.w;
    r1.x = acc[4] * sc + b1.x; r1.y = acc[5] * sc + b1.y;
    r1.z = acc[6] * sc + b1.z; r1.w = acc[7] * sc + b1.w;
    float* o = out + (size_t)d * 40 + q * 8;
    *(float4*)o = r0;
    *(float4*)(o + 4) = r1;
}

// ---------------- launch ----------------

extern "C" void kernel_launch(void* const* d_in, const int* in_sizes, int n_in,
                              void* d_out, int out_size, void* d_ws, size_t ws_size,
                              hipStream_t stream) {
    const float* x  = (const float*)d_in[0];
    const int*   ei = (const int*)d_in[1];
    const float* W1 = (const float*)d_in[2];
    const float* g1 = (const float*)d_in[4];
    const float* be1= (const float*)d_in[5];
    const float* W2 = (const float*)d_in[6];
    const float* g2 = (const float*)d_in[8];
    const float* be2= (const float*)d_in[9];
    const float* W3 = (const float*)d_in[10];
    const float* b3 = (const float*)d_in[11];

    const int N = in_sizes[0] / 128;
    const int E = in_sizes[1] / 2;
    const int* srcv = ei;
    const int* dstv = ei + E;
    const int NB = (N + 255) / 256;
    const int RS = (N + 7) / 8;
    const int EB8 = 8 * ((E + 255) / 256);

    __half* M    = (__half*)d_ws;                 // N*128
    __half* Hb   = M + (size_t)N * 128;           // N*128
    __half* t3   = Hb + (size_t)N * 128;          // N*64 (padded)
    __half* Wt1  = t3 + (size_t)N * 64;           // 128*128
    __half* Wt2  = Wt1 + 128 * 128;
    __half* Wt3  = Wt2 + 128 * 128;               // 48*128
    float* dinv    = (float*)(Wt3 + 48 * 128);
    int*   deg     = (int*)(dinv + N);            // N  (zero block start)
    float* sumsA   = (float*)(deg + N);           // 32*128
    float* sumsqA  = sumsA + 32 * 128;
    float* sumsB   = sumsqA + 32 * 128;
    float* sumsqB  = sumsB + 32 * 128;
    int*   row_ptr = (int*)(sumsqB + 32 * 128);   // N+1
    int*   cursor  = row_ptr + N + 1;             // N
    unsigned short* sidx = (unsigned short*)(cursor + N);  // E (uint16)
    int*   bsum    = (int*)(sidx + E);            // 256
    float* out     = (float*)d_out;

    const int GB = (N + 127) / 128;
    const int ZN = N + 4 * 32 * 128;

    // ---- setup: pack weights, zero, CSR build ----
    k_packW3<<<(2 * 128 * 128 + 48 * 128 + 255) / 256, 256, 0, stream>>>(W1, W2, W3, Wt1, Wt2, Wt3);
    k_zeroz<<<(ZN + 255) / 256, 256, 0, stream>>>(deg, ZN);
    k_deg_xcd<<<EB8, 256, 0, stream>>>(dstv, deg, E, RS);
    k_chunkscan<<<1, 256, 0, stream>>>(deg, bsum, N);
    k_scanchunk<<<NB, 256, 0, stream>>>(deg, bsum, row_ptr, cursor, dinv, N, E);
    k_place_xcd<<<EB8, 256, 0, stream>>>(srcv, dstv, cursor, sidx, E, RS);

    // ---- layer 1 ----
    k_gemm_mfma<4, 128, 128, 0, 2><<<GB * 2, 256, 0, stream>>>(x, Wt1, nullptr, nullptr, nullptr, nullptr, dinv, M, N);
    k_agg128_stats<<<(N + 15) / 16, 256, 0, stream>>>(M, row_ptr, sidx, dinv, Hb, sumsA, sumsqA, N);

    // ---- layer 2 (BN1 fused into GEMM) ----
    k_gemm_mfma<4, 128, 128, 1, 2><<<GB * 2, 256, 0, stream>>>(Hb, Wt2, sumsA, sumsqA, g1, be1, dinv, M, N);
    k_agg128_stats<<<(N + 15) / 16, 256, 0, stream>>>(M, row_ptr, sidx, dinv, Hb, sumsB, sumsqB, N);

    // ---- layer 3 (BN2 fused into GEMM, t3 padded to stride 64) ----
    k_gemm_mfma<3, 64, 40, 1, 1><<<GB, 256, 0, stream>>>(Hb, Wt3, sumsB, sumsqB, g2, be2, dinv, t3, N);
    k_agg40_f16<<<(N * 5 + 255) / 256, 256, 0, stream>>>(t3, row_ptr, sidx, dinv, b3, out, N);
}